// Round 10
// baseline (965.505 us; speedup 1.0000x reference)
//
#include <hip/hip_runtime.h>
#include <math.h>

#define B_   32
#define SEQ_ 2048
#define DIM_ 512
#define KSEL 128

typedef _Float16 f16;
typedef _Float16 half8 __attribute__((ext_vector_type(8)));
typedef _Float16 half4 __attribute__((ext_vector_type(4)));
typedef float floatx4 __attribute__((ext_vector_type(4)));

__device__ __forceinline__ float gelu_exact(float v) {
  return 0.5f * v * (1.0f + erff(v * 0.70710678118654752440f));
}

// ======================= stats kernels =======================
__global__ __launch_bounds__(256) void rowstats512(const float* __restrict__ X,
                                                   float* __restrict__ mean,
                                                   float* __restrict__ rstd) {
  int row = blockIdx.x * 4 + (threadIdx.x >> 6);
  int l = threadIdx.x & 63;
  const float4* p = (const float4*)(X + (size_t)row * 512);
  float4 v0 = p[l * 2], v1 = p[l * 2 + 1];
  float s = v0.x + v0.y + v0.z + v0.w + v1.x + v1.y + v1.z + v1.w;
  float q = v0.x*v0.x + v0.y*v0.y + v0.z*v0.z + v0.w*v0.w
          + v1.x*v1.x + v1.y*v1.y + v1.z*v1.z + v1.w*v1.w;
#pragma unroll
  for (int off = 32; off > 0; off >>= 1) {
    s += __shfl_down(s, off);
    q += __shfl_down(q, off);
  }
  if (l == 0) {
    float m = s * (1.0f / 512.0f);
    float var = q * (1.0f / 512.0f) - m * m;
    mean[row] = m;
    rstd[row] = rsqrtf(var + 1e-5f);
  }
}

__global__ __launch_bounds__(256) void rowstats512_f16(const f16* __restrict__ X,
                                                       float* __restrict__ mean,
                                                       float* __restrict__ rstd) {
  int row = blockIdx.x * 4 + (threadIdx.x >> 6);
  int l = threadIdx.x & 63;
  half8 h = *(const half8*)(X + (size_t)row * 512 + l * 8);
  float s = 0.f, q = 0.f;
#pragma unroll
  for (int i = 0; i < 8; ++i) { float v = (float)h[i]; s += v; q += v * v; }
#pragma unroll
  for (int off = 32; off > 0; off >>= 1) {
    s += __shfl_down(s, off);
    q += __shfl_down(q, off);
  }
  if (l == 0) {
    float m = s * (1.0f / 512.0f);
    float var = q * (1.0f / 512.0f) - m * m;
    mean[row] = m;
    rstd[row] = rsqrtf(var + 1e-5f);
  }
}

__global__ __launch_bounds__(512) void colstats_part(const f16* __restrict__ xtok,
                                                     float2* __restrict__ part) {
  int b = blockIdx.x >> 3, pr = blockIdx.x & 7;
  int d = threadIdx.x;
  const f16* src = xtok + ((size_t)b * SEQ_ + (size_t)pr * 256) * 512 + d;
  float s = 0.f, q = 0.f;
#pragma unroll 4
  for (int i = 0; i < 256; ++i) {
    float v = (float)src[(size_t)i * 512];
    s += v; q += v * v;
  }
  part[(size_t)blockIdx.x * 512 + d] = make_float2(s, q);
}

__global__ __launch_bounds__(256) void colstats_fin(const float2* __restrict__ part,
                                                    float* __restrict__ mean,
                                                    float* __restrict__ rstd) {
  int idx = blockIdx.x * 256 + threadIdx.x;
  int b = idx >> 9;
  float s = 0.f, q = 0.f;
#pragma unroll
  for (int p = 0; p < 8; ++p) {
    float2 v = part[((size_t)(b * 8 + p)) * 512 + (idx & 511)];
    s += v.x; q += v.y;
  }
  float m = s * (1.0f / 2048.0f);
  mean[idx] = m;
  rstd[idx] = rsqrtf(q * (1.0f / 2048.0f) - m * m + 1e-5f);
}

// ======================= transpose / convert =======================
template <typename T>
__global__ __launch_bounds__(256) void transpose_cvt(const T* __restrict__ src,
                                                     f16* __restrict__ dst,
                                                     int R, int C, long sb, long db) {
  __shared__ float tile[32][33];
  const T* s = src + (long)blockIdx.z * sb;
  f16* d = dst + (long)blockIdx.z * db;
  int c0 = blockIdx.x * 32, r0 = blockIdx.y * 32;
  int tx = threadIdx.x, ty = threadIdx.y;
#pragma unroll
  for (int i = 0; i < 4; ++i) {
    int r = r0 + ty + i * 8, c = c0 + tx;
    if (r < R && c < C) tile[ty + i * 8][tx] = (float)s[(long)r * C + c];
  }
  __syncthreads();
#pragma unroll
  for (int i = 0; i < 4; ++i) {
    int c = c0 + ty + i * 8, r = r0 + tx;
    if (c < C && r < R) d[(long)c * R + r] = (f16)tile[tx][ty + i * 8];
  }
}

// LN2-apply + transpose: A2[b][d][s] = (xtok[b][s][d]-m2[b,d])*r2[b,d]*g2[s]+bl2[s]
__global__ __launch_bounds__(256) void trans2_kernel(const f16* __restrict__ xtok,
    const float* __restrict__ mean2, const float* __restrict__ rstd2,
    const float* __restrict__ g2, const float* __restrict__ bl2,
    f16* __restrict__ A2) {
  __shared__ float tile[32][33];
  int b = blockIdx.z;
  const f16* src = xtok + (long)b * SEQ_ * 512;
  f16* dst = A2 + (long)b * 512 * SEQ_;
  int d0 = blockIdx.x * 32, s0 = blockIdx.y * 32;
  int tx = threadIdx.x, ty = threadIdx.y;
  float m = mean2[b * 512 + d0 + tx];
  float rs = rstd2[b * 512 + d0 + tx];
#pragma unroll
  for (int i = 0; i < 4; ++i) {
    int s = s0 + ty + i * 8;
    float v = (float)src[(long)s * 512 + d0 + tx];
    tile[ty + i * 8][tx] = (v - m) * rs * g2[s] + bl2[s];
  }
  __syncthreads();
#pragma unroll
  for (int i = 0; i < 4; ++i) {
    int d = d0 + ty + i * 8, s = s0 + tx;
    dst[(long)d * SEQ_ + s] = (f16)tile[tx][ty + i * 8];
  }
}

// ======================= T3-min double-buffered 128x128 BK=64 engine =======================
// 256 threads = 4 waves (2x2), per-wave 64x64 out (4x4 16x16 frags), acc fp32.
// LDS per operand: [2 dbuf][2 kk-halves][128 rows x 32 halves] (64B rows,
// slot XOR-swizzle ^((row>>1)&3), measured conflict-free). Total 64KB -> 2 blocks/CU.
// Per K-tile: STAGE(t+1 -> buf^1) issued BEFORE reads+MFMA of buf; ONE __syncthreads.

// stage a [128][64h] K-tile as two [128][32h] halves via global_load_lds (8 gll/thread... 4 here per op)
__device__ __forceinline__ void stage_tile_gll(const f16* __restrict__ src, long ld,
                                               int k0, f16* D0, f16* D1, int t) {
  int w = t >> 6;
#pragma unroll
  for (int kk = 0; kk < 2; ++kk) {
    f16* dst = kk ? D1 : D0;
#pragma unroll
    for (int s = 0; s < 2; ++s) {
      int row = s * 64 + (t >> 2);                 // 0..127
      int slot = (t & 3) ^ ((row >> 1) & 3);       // pre-swizzled source col
      const f16* g = src + (long)row * ld + k0 + kk * 32 + slot * 8;
      f16* lp = dst + (long)(s * 64 + w * 16) * 32;  // wave-uniform; HW adds lane*16B
      __builtin_amdgcn_global_load_lds(
          (const __attribute__((address_space(1))) void*)g,
          (__attribute__((address_space(3))) void*)lp, 16, 0, 0);
    }
  }
}

// reg-staged A K-tile with LN fused, fp32 source (32 halves/thread)
__device__ __forceinline__ void stage_a_ln_f32_64(const float* __restrict__ src, long ld,
    const float* __restrict__ mean, const float* __restrict__ rstd,
    const float* __restrict__ g, const float* __restrict__ bl,
    int row0, int k0, f16* D0, f16* D1, int t) {
  int row = t >> 1, kk = t & 1;
  int r = row0 + row;
  float m = mean[r], sd = rstd[r];
  f16* dst = (kk ? D1 : D0) + row * 32;
  int swz = (row >> 1) & 3;
  const float* p = src + (long)r * ld + k0 + kk * 32;
  const float* gp = g + k0 + kk * 32;
  const float* bp = bl + k0 + kk * 32;
#pragma unroll
  for (int j = 0; j < 4; ++j) {
    float4 q0 = *(const float4*)(p + j * 8);
    float4 q1 = *(const float4*)(p + j * 8 + 4);
    float4 g0 = *(const float4*)(gp + j * 8);
    float4 g1 = *(const float4*)(gp + j * 8 + 4);
    float4 b0 = *(const float4*)(bp + j * 8);
    float4 b1 = *(const float4*)(bp + j * 8 + 4);
    half8 o;
    o[0] = (f16)((q0.x - m) * sd * g0.x + b0.x);
    o[1] = (f16)((q0.y - m) * sd * g0.y + b0.y);
    o[2] = (f16)((q0.z - m) * sd * g0.z + b0.z);
    o[3] = (f16)((q0.w - m) * sd * g0.w + b0.w);
    o[4] = (f16)((q1.x - m) * sd * g1.x + b1.x);
    o[5] = (f16)((q1.y - m) * sd * g1.y + b1.y);
    o[6] = (f16)((q1.z - m) * sd * g1.z + b1.z);
    o[7] = (f16)((q1.w - m) * sd * g1.w + b1.w);
    *(half8*)(dst + ((j ^ swz) << 3)) = o;
  }
}

// reg-staged A K-tile with LN fused, f16 source
__device__ __forceinline__ void stage_a_ln_f16_64(const f16* __restrict__ src, long ld,
    const float* __restrict__ mean, const float* __restrict__ rstd,
    const float* __restrict__ g, const float* __restrict__ bl,
    int row0, int k0, f16* D0, f16* D1, int t) {
  int row = t >> 1, kk = t & 1;
  int r = row0 + row;
  float m = mean[r], sd = rstd[r];
  f16* dst = (kk ? D1 : D0) + row * 32;
  int swz = (row >> 1) & 3;
  const f16* p = src + (long)r * ld + k0 + kk * 32;
  const float* gp = g + k0 + kk * 32;
  const float* bp = bl + k0 + kk * 32;
#pragma unroll
  for (int j = 0; j < 4; ++j) {
    half8 h = *(const half8*)(p + j * 8);
    float4 g0 = *(const float4*)(gp + j * 8);
    float4 g1 = *(const float4*)(gp + j * 8 + 4);
    float4 b0 = *(const float4*)(bp + j * 8);
    float4 b1 = *(const float4*)(bp + j * 8 + 4);
    half8 o;
    o[0] = (f16)(((float)h[0] - m) * sd * g0.x + b0.x);
    o[1] = (f16)(((float)h[1] - m) * sd * g0.y + b0.y);
    o[2] = (f16)(((float)h[2] - m) * sd * g0.z + b0.z);
    o[3] = (f16)(((float)h[3] - m) * sd * g0.w + b0.w);
    o[4] = (f16)(((float)h[4] - m) * sd * g1.x + b1.x);
    o[5] = (f16)(((float)h[5] - m) * sd * g1.y + b1.y);
    o[6] = (f16)(((float)h[6] - m) * sd * g1.z + b1.z);
    o[7] = (f16)(((float)h[7] - m) * sd * g1.w + b1.w);
    *(half8*)(dst + ((j ^ swz) << 3)) = o;
  }
}

__device__ __forceinline__ half8 frag32(const f16* buf, int row, int sl) {
  return *(const half8*)(buf + (long)row * 32 + ((sl ^ ((row >> 1) & 3)) << 3));
}

// one K-tile of compute from buf halves (A0/A1, B0/B1): 32 MFMA
__device__ __forceinline__ void tile_mfma(const f16* A0, const f16* A1,
                                          const f16* B0, const f16* B1,
                                          int wr, int wc, int rl, int sl,
                                          floatx4 acc[4][4]) {
  half8 afr[4], bfr[4];
#pragma unroll
  for (int kk = 0; kk < 2; ++kk) {
    const f16* Ab = kk ? A1 : A0;
    const f16* Bb = kk ? B1 : B0;
#pragma unroll
    for (int mi = 0; mi < 4; ++mi) afr[mi] = frag32(Ab, wr * 64 + mi * 16 + rl, sl);
#pragma unroll
    for (int ni = 0; ni < 4; ++ni) bfr[ni] = frag32(Bb, wc * 64 + ni * 16 + rl, sl);
    __builtin_amdgcn_s_setprio(1);
#pragma unroll
    for (int mi = 0; mi < 4; ++mi)
#pragma unroll
      for (int ni = 0; ni < 4; ++ni)
        acc[mi][ni] = __builtin_amdgcn_mfma_f32_16x16x32_f16(afr[mi], bfr[ni], acc[mi][ni], 0, 0, 0);
    __builtin_amdgcn_s_setprio(0);
  }
}

#define ENGINE_PROLOG \
  __shared__ __attribute__((aligned(16))) f16 Ah[2][2][128 * 32]; \
  __shared__ __attribute__((aligned(16))) f16 Bh[2][2][128 * 32]; \
  int t = threadIdx.x; \
  int lane = t & 63, w = t >> 6, wr = w >> 1, wc = w & 1; \
  int rl = lane & 15, sl = lane >> 4; \
  floatx4 acc[4][4]; \
  _Pragma("unroll") for (int mi = 0; mi < 4; ++mi) \
  _Pragma("unroll") for (int ni = 0; ni < 4; ++ni) acc[mi][ni] = (floatx4){0.f,0.f,0.f,0.f};

// ---- G1: x_tok = gelu(ln1(x)@W1 + b1).  grid (4, 512), K=512 ----
__global__ __launch_bounds__(256) void g1_kernel(const float* __restrict__ x,
    const float* __restrict__ mean, const float* __restrict__ rstd,
    const float* __restrict__ g1, const float* __restrict__ bl1,
    const f16* __restrict__ W1T, const float* __restrict__ b1,
    f16* __restrict__ xtok) {
  ENGINE_PROLOG
  int m0 = blockIdx.y * 128, n0 = blockIdx.x * 128;
  const int NT = 512 / 64;
  stage_a_ln_f32_64(x, 512, mean, rstd, g1, bl1, m0, 0, Ah[0][0], Ah[0][1], t);
  stage_tile_gll(W1T + (long)n0 * 512, 512, 0, Bh[0][0], Bh[0][1], t);
  __syncthreads();
  for (int kt = 0; kt < NT; ++kt) {
    int c = kt & 1;
    if (kt + 1 < NT) {
      stage_a_ln_f32_64(x, 512, mean, rstd, g1, bl1, m0, (kt + 1) * 64,
                        Ah[c ^ 1][0], Ah[c ^ 1][1], t);
      stage_tile_gll(W1T + (long)n0 * 512, 512, (kt + 1) * 64,
                     Bh[c ^ 1][0], Bh[c ^ 1][1], t);
    }
    tile_mfma(Ah[c][0], Ah[c][1], Bh[c][0], Bh[c][1], wr, wc, rl, sl, acc);
    __syncthreads();
  }
#pragma unroll
  for (int mi = 0; mi < 4; ++mi)
#pragma unroll
    for (int ni = 0; ni < 4; ++ni) {
      int cc = n0 + wc * 64 + ni * 16 + rl;
      float bias = b1[cc];
      int r0 = m0 + wr * 64 + mi * 16 + sl * 4;
#pragma unroll
      for (int j = 0; j < 4; ++j)
        xtok[(long)(r0 + j) * 512 + cc] = (f16)gelu_exact(acc[mi][ni][j] + bias);
    }
}

// ---- G2: xsum = xtok + gelu(W2T @ A2^T + b2). grid (4, 16, 32), K=2048 ----
__global__ __launch_bounds__(256) void g2_kernel(const f16* __restrict__ W2T,
    const f16* __restrict__ A2, const float* __restrict__ b2,
    const f16* __restrict__ xtok, f16* __restrict__ xsum) {
  ENGINE_PROLOG
  int b = blockIdx.z;
  int m0 = blockIdx.y * 128, n0 = blockIdx.x * 128;
  const f16* Am = W2T + (long)m0 * SEQ_;
  const f16* Bm = A2 + (long)b * 512 * SEQ_ + (long)n0 * SEQ_;
  const f16* xtb = xtok + (long)b * SEQ_ * 512;
  f16* xsb = xsum + (long)b * SEQ_ * 512;
  const int NT = SEQ_ / 64;
  stage_tile_gll(Am, SEQ_, 0, Ah[0][0], Ah[0][1], t);
  stage_tile_gll(Bm, SEQ_, 0, Bh[0][0], Bh[0][1], t);
  __syncthreads();
  for (int kt = 0; kt < NT; ++kt) {
    int c = kt & 1;
    if (kt + 1 < NT) {
      stage_tile_gll(Am, SEQ_, (kt + 1) * 64, Ah[c ^ 1][0], Ah[c ^ 1][1], t);
      stage_tile_gll(Bm, SEQ_, (kt + 1) * 64, Bh[c ^ 1][0], Bh[c ^ 1][1], t);
    }
    tile_mfma(Ah[c][0], Ah[c][1], Bh[c][0], Bh[c][1], wr, wc, rl, sl, acc);
    __syncthreads();
  }
#pragma unroll
  for (int mi = 0; mi < 4; ++mi)
#pragma unroll
    for (int ni = 0; ni < 4; ++ni) {
      int cc = n0 + wc * 64 + ni * 16 + rl;
      int r0 = m0 + wr * 64 + mi * 16 + sl * 4;
#pragma unroll
      for (int j = 0; j < 4; ++j) {
        int r = r0 + j;
        long idx = (long)r * 512 + cc;
        float v = gelu_exact(acc[mi][ni][j] + b2[r]);
        xsb[idx] = (f16)((float)xtb[idx] + v);
      }
    }
}

// ---- G3: xproj = ln3(xsum)@W3[:,1:] + b3[1:], dual-write xprojT. grid (4,512) ----
__global__ __launch_bounds__(256) void g3_kernel(const f16* __restrict__ xsum,
    const float* __restrict__ mean, const float* __restrict__ rstd,
    const float* __restrict__ g3, const float* __restrict__ bl3,
    const f16* __restrict__ BT /* = W3T + 512 */, const float* __restrict__ b3,
    f16* __restrict__ xproj, f16* __restrict__ xprojT) {
  ENGINE_PROLOG
  int m0 = blockIdx.y * 128, n0 = blockIdx.x * 128;
  const int NT = 512 / 64;
  stage_a_ln_f16_64(xsum, 512, mean, rstd, g3, bl3, m0, 0, Ah[0][0], Ah[0][1], t);
  stage_tile_gll(BT + (long)n0 * 512, 512, 0, Bh[0][0], Bh[0][1], t);
  __syncthreads();
  for (int kt = 0; kt < NT; ++kt) {
    int c = kt & 1;
    if (kt + 1 < NT) {
      stage_a_ln_f16_64(xsum, 512, mean, rstd, g3, bl3, m0, (kt + 1) * 64,
                        Ah[c ^ 1][0], Ah[c ^ 1][1], t);
      stage_tile_gll(BT + (long)n0 * 512, 512, (kt + 1) * 64,
                     Bh[c ^ 1][0], Bh[c ^ 1][1], t);
    }
    tile_mfma(Ah[c][0], Ah[c][1], Bh[c][0], Bh[c][1], wr, wc, rl, sl, acc);
    __syncthreads();
  }
#pragma unroll
  for (int mi = 0; mi < 4; ++mi)
#pragma unroll
    for (int ni = 0; ni < 4; ++ni) {
      int cc = n0 + wc * 64 + ni * 16 + rl;
      float bias = b3[cc + 1];
      int r0 = m0 + wr * 64 + mi * 16 + sl * 4;
      half4 xp;
#pragma unroll
      for (int j = 0; j < 4; ++j) {
        f16 v = (f16)(acc[mi][ni][j] + bias);
        xproj[(long)(r0 + j) * 512 + cc] = v;
        xp[j] = v;
      }
      long bb = r0 >> 11;
      long rloc = r0 & 2047;
      *(half4*)(xprojT + (bb * 512 + cc) * SEQ_ + rloc) = xp;
    }
}

// ---- score ----
__global__ __launch_bounds__(256) void score_kernel(const f16* __restrict__ xsum,
    const float* __restrict__ mean, const float* __restrict__ rstd,
    const float* __restrict__ g3, const float* __restrict__ bl3,
    const f16* __restrict__ w3c, const float* __restrict__ b3,
    float* __restrict__ xscore) {
  int row = blockIdx.x * 4 + (threadIdx.x >> 6);
  int l = threadIdx.x & 63;
  float m = mean[row], sd = rstd[row];
  half8 h = *(const half8*)(xsum + (long)row * 512 + l * 8);
  half8 wv = *(const half8*)(w3c + l * 8);
  float acc = 0.f;
#pragma unroll
  for (int i = 0; i < 8; ++i) {
    int d = l * 8 + i;
    float v = ((float)h[i] - m) * sd * g3[d] + bl3[d];
    acc += v * (float)wv[i];
  }
#pragma unroll
  for (int off = 32; off > 0; off >>= 1) acc += __shfl_down(acc, off);
  if (l == 0) xscore[row] = acc + b3[0];
}

// ---- diff_topk: 512 threads, 4 elems/lane, single barrier/iter ----
__global__ __launch_bounds__(512) void topk_kernel(const float* __restrict__ xscore,
                                                   const float* __restrict__ tau,
                                                   f16* __restrict__ Wm) {
  int b = blockIdx.x, t = threadIdx.x;
  __shared__ float red[2][8];
  float tv = fminf(fmaxf(tau[0], -2.0f), 5.0f);
  float temp = 1.0f / (1.0f + expf(-tv));
  float it = 1.0f / temp;
  float c[4];
  const float* xs = xscore + (size_t)b * SEQ_;
  {
    float4 v = *(const float4*)(xs + t * 4);
    c[0] = v.x; c[1] = v.y; c[2] = v.z; c[3] = v.w;
  }
  int l = t & 63, wid = t >> 6;
  for (int k = 0; k < KSEL; ++k) {
    float e[4];
    float p = 0.f;
#pragma unroll
    for (int i = 0; i < 4; ++i) { e[i] = expf(c[i] * it); p += e[i]; }
#pragma unroll
    for (int off = 32; off > 0; off >>= 1) p += __shfl_down(p, off);
    if (l == 0) red[k & 1][wid] = p;
    __syncthreads();
    float S = 0.f;
#pragma unroll
    for (int q = 0; q < 8; ++q) S += red[k & 1][q];
    float iS = 1.0f / S;
    half4 h;
    float a[4];
#pragma unroll
    for (int i = 0; i < 4; ++i) { a[i] = e[i] * iS; h[i] = (f16)a[i]; }
    *(half4*)(Wm + ((size_t)b * KSEL + k) * SEQ_ + t * 4) = h;
#pragma unroll
    for (int i = 0; i < 4; ++i) c[i] += logf(fmaxf(1.0f - a[i], 1e-6f));
  }
}

// ---- GZ (split-K=2): grid (4, 2, 32), M=128, K=1024 each ----
__global__ __launch_bounds__(256) void gz_kernel(const f16* __restrict__ Wm,
    const f16* __restrict__ xprojT, float* __restrict__ Zpart) {
  ENGINE_PROLOG
  int b = blockIdx.z, kc = blockIdx.y;
  int n0 = blockIdx.x * 128;
  const f16* Am = Wm + (long)b * KSEL * SEQ_;
  const f16* Bm = xprojT + (long)b * 512 * SEQ_ + (long)n0 * SEQ_;
  float* Zb = Zpart + ((long)b * 2 + kc) * KSEL * 512;
  int kbeg = kc * 1024;
  const int NT = 1024 / 64;
  stage_tile_gll(Am, SEQ_, kbeg, Ah[0][0], Ah[0][1], t);
  stage_tile_gll(Bm, SEQ_, kbeg, Bh[0][0], Bh[0][1], t);
  __syncthreads();
  for (int kt = 0; kt < NT; ++kt) {
    int c = kt & 1;
    if (kt + 1 < NT) {
      stage_tile_gll(Am, SEQ_, kbeg + (kt + 1) * 64, Ah[c ^ 1][0], Ah[c ^ 1][1], t);
      stage_tile_gll(Bm, SEQ_, kbeg + (kt + 1) * 64, Bh[c ^ 1][0], Bh[c ^ 1][1], t);
    }
    tile_mfma(Ah[c][0], Ah[c][1], Bh[c][0], Bh[c][1], wr, wc, rl, sl, acc);
    __syncthreads();
  }
#pragma unroll
  for (int mi = 0; mi < 4; ++mi)
#pragma unroll
    for (int ni = 0; ni < 4; ++ni) {
      int cc = n0 + wc * 64 + ni * 16 + rl;
      int r0 = wr * 64 + mi * 16 + sl * 4;
#pragma unroll
      for (int j = 0; j < 4; ++j)
        Zb[(long)(r0 + j) * 512 + cc] = acc[mi][ni][j];
    }
}

// ---- reduce split-K + transpose -> ZT ----
__global__ __launch_bounds__(256) void ztrans_kernel(const float* __restrict__ Zpart,
                                                     f16* __restrict__ ZT) {
  __shared__ float tile[32][33];
  int b = blockIdx.z;
  int c0 = blockIdx.x * 32, r0 = blockIdx.y * 32;
  int tx = threadIdx.x, ty = threadIdx.y;
  const float* p0 = Zpart + ((long)b * 2 + 0) * KSEL * 512;
  const float* p1 = Zpart + ((long)b * 2 + 1) * KSEL * 512;
#pragma unroll
  for (int i = 0; i < 4; ++i) {
    int r = r0 + ty + i * 8, c = c0 + tx;
    tile[ty + i * 8][tx] = p0[(long)r * 512 + c] + p1[(long)r * 512 + c];
  }
  __syncthreads();
  f16* d = ZT + (long)b * 512 * KSEL;
#pragma unroll
  for (int i = 0; i < 4; ++i) {
    int c = c0 + ty + i * 8, r = r0 + tx;
    d[(long)c * KSEL + r] = (f16)tile[tx][ty + i * 8];
  }
}

// ---- GY: rbuf = xproj + Wm^T @ Z. grid (4, 16, 32), K=128 ----
__global__ __launch_bounds__(256) void gy_kernel(const f16* __restrict__ WmT,
    const f16* __restrict__ ZT, const f16* __restrict__ xproj,
    f16* __restrict__ rbuf) {
  ENGINE_PROLOG
  int b = blockIdx.z;
  int m0 = blockIdx.y * 128, n0 = blockIdx.x * 128;
  const f16* Am = WmT + (long)b * SEQ_ * KSEL + (long)m0 * KSEL;
  const f16* Bm = ZT + (long)b * 512 * KSEL + (long)n0 * KSEL;
  const f16* xpb = xproj + (long)b * SEQ_ * 512;
  f16* rb = rbuf + (long)b * SEQ_ * 512;
  const int NT = KSEL / 64;
  stage_tile_gll(Am, KSEL, 0, Ah[0][0], Ah[0][1], t);
  stage_tile_gll(Bm, KSEL, 0, Bh[0][0], Bh[0][1], t);
  __syncthreads();
  for (int kt = 0; kt < NT; ++kt) {
    int c = kt & 1;
    if (kt + 1 < NT) {
      stage_tile_gll(Am, KSEL, (kt + 1) * 64, Ah[c ^ 1][0], Ah[c ^ 1][1], t);
      stage_tile_gll(Bm, KSEL, (kt + 1) * 64, Bh[c ^ 1][0], Bh[c ^ 1][1], t);
    }
    tile_mfma(Ah[c][0], Ah[c][1], Bh[c][0], Bh[c][1], wr, wc, rl, sl, acc);
    __syncthreads();
  }
#pragma unroll
  for (int mi = 0; mi < 4; ++mi)
#pragma unroll
    for (int ni = 0; ni < 4; ++ni) {
      int cc = n0 + wc * 64 + ni * 16 + rl;
      int r0 = m0 + wr * 64 + mi * 16 + sl * 4;
#pragma unroll
      for (int j = 0; j < 4; ++j) {
        long idx = (long)(r0 + j) * 512 + cc;
        rb[idx] = (f16)((float)xpb[idx] + acc[mi][ni][j]);
      }
    }
}

// ---- G4: out = ln4(rbuf)@W4 + b4 (fp32 out). grid (4, 512) ----
__global__ __launch_bounds__(256) void g4_kernel(const f16* __restrict__ rbuf,
    const float* __restrict__ mean, const float* __restrict__ rstd,
    const float* __restrict__ g4, const float* __restrict__ bl4,
    const f16* __restrict__ W4T, const float* __restrict__ b4,
    float* __restrict__ out) {
  ENGINE_PROLOG
  int m0 = blockIdx.y * 128, n0 = blockIdx.x * 128;
  const int NT = 512 / 64;
  stage_a_ln_f16_64(rbuf, 512, mean, rstd, g4, bl4, m0, 0, Ah[0][0], Ah[0][1], t);
  stage_tile_gll(W4T + (long)n0 * 512, 512, 0, Bh[0][0], Bh[0][1], t);
  __syncthreads();
  for (int kt = 0; kt < NT; ++kt) {
    int c = kt & 1;
    if (kt + 1 < NT) {
      stage_a_ln_f16_64(rbuf, 512, mean, rstd, g4, bl4, m0, (kt + 1) * 64,
                        Ah[c ^ 1][0], Ah[c ^ 1][1], t);
      stage_tile_gll(W4T + (long)n0 * 512, 512, (kt + 1) * 64,
                     Bh[c ^ 1][0], Bh[c ^ 1][1], t);
    }
    tile_mfma(Ah[c][0], Ah[c][1], Bh[c][0], Bh[c][1], wr, wc, rl, sl, acc);
    __syncthreads();
  }
#pragma unroll
  for (int mi = 0; mi < 4; ++mi)
#pragma unroll
    for (int ni = 0; ni < 4; ++ni) {
      int cc = n0 + wc * 64 + ni * 16 + rl;
      float bias = b4[cc];
      int r0 = m0 + wr * 64 + mi * 16 + sl * 4;
#pragma unroll
      for (int j = 0; j < 4; ++j)
        out[(long)(r0 + j) * 512 + cc] = acc[mi][ni][j] + bias;
    }
}

// ======================= launcher =======================
extern "C" void kernel_launch(void* const* d_in, const int* in_sizes, int n_in,
                              void* d_out, int out_size, void* d_ws, size_t ws_size,
                              hipStream_t stream) {
  const float* x    = (const float*)d_in[0];
  const float* tau  = (const float*)d_in[1];
  const float* g1   = (const float*)d_in[2];
  const float* bl1  = (const float*)d_in[3];
  const float* W1   = (const float*)d_in[4];
  const float* b1   = (const float*)d_in[5];
  const float* g2   = (const float*)d_in[6];
  const float* bl2  = (const float*)d_in[7];
  const float* W2   = (const float*)d_in[8];
  const float* b2   = (const float*)d_in[9];
  const float* g3   = (const float*)d_in[10];
  const float* bl3  = (const float*)d_in[11];
  const float* W3   = (const float*)d_in[12];
  const float* b3   = (const float*)d_in[13];
  const float* g4   = (const float*)d_in[14];
  const float* bl4  = (const float*)d_in[15];
  const float* W4   = (const float*)d_in[16];
  const float* b4   = (const float*)d_in[17];
  float* out = (float*)d_out;

  const long NTOK = (long)B_ * SEQ_;  // 65536

  // ---- workspace layout ----
  char* ws = (char*)d_ws;
  f16* regA   = (f16*)(ws);                         // 64MB: A2, later xproj
  f16* regB   = (f16*)(ws + (64l << 20));           // 64MB: xsum, later rbuf
  float* Zpart = (float*)(ws + (128l << 20));       // 16MB (split-K=2 fp32)
  f16* W2T    = (f16*)(ws + (144l << 20));          // 8MB
  f16* W1T    = (f16*)(ws + (152l << 20));          // 0.5MB
  f16* W3T    = (f16*)(ws + (153l << 20));          // 0.51MB
  f16* W4T    = (f16*)(ws + (154l << 20));          // 0.5MB
  float* xscore = (float*)(ws + (155l << 20));      // 0.25MB
  float* meanA  = (float*)(ws + (156l << 20));      // 0.25MB
  float* rstdA  = meanA + NTOK;                     // 0.25MB
  float* mean2  = rstdA + NTOK;                     // 64KB
  float* rstd2  = mean2 + B_ * 512;                 // 64KB
  float2* part  = (float2*)(rstd2 + B_ * 512);      // 1MB
  f16* ZT     = (f16*)(ws + (157l << 20));          // 4MB

  // ---- d_out (128MB) doubles as scratch, fully overwritten by G4 ----
  f16* xtok   = (f16*)d_out;                               // [0,64) until g2 reads it
  f16* xprojT = (f16*)d_out;                               // [0,64) written by g3 (xtok dead)
  f16* Wm     = (f16*)((char*)d_out + (64l << 20));        // [64,80)
  f16* WmT    = (f16*)((char*)d_out + (80l << 20));        // [80,96)

  f16* A2    = regA;
  f16* xsum  = regB;
  f16* xproj = regA;   // A2 dead after G2
  f16* rbuf  = regB;   // xsum dead after G3

  dim3 tb(32, 8);

  // weight transposes (f16, [n][k])
  transpose_cvt<float><<<dim3(16, 16, 1), tb, 0, stream>>>(W1, W1T, 512, 512, 0, 0);
  transpose_cvt<float><<<dim3(64, 64, 1), tb, 0, stream>>>(W2, W2T, 2048, 2048, 0, 0);
  transpose_cvt<float><<<dim3(17, 16, 1), tb, 0, stream>>>(W3, W3T, 512, 513, 0, 0);
  transpose_cvt<float><<<dim3(16, 16, 1), tb, 0, stream>>>(W4, W4T, 512, 512, 0, 0);

  // 1) LN1 stats + G1 -> xtok (f16, in d_out)
  rowstats512<<<NTOK / 4, 256, 0, stream>>>(x, meanA, rstdA);
  g1_kernel<<<dim3(4, 512), 256, 0, stream>>>(x, meanA, rstdA, g1, bl1, W1T, b1, xtok);

  // 2) LN2 stats + transposed normalize -> A2, then G2 -> xsum
  colstats_part<<<B_ * 8, 512, 0, stream>>>(xtok, part);
  colstats_fin<<<64, 256, 0, stream>>>(part, mean2, rstd2);
  trans2_kernel<<<dim3(16, 64, B_), tb, 0, stream>>>(xtok, mean2, rstd2, g2, bl2, A2);
  g2_kernel<<<dim3(4, 16, B_), 256, 0, stream>>>(W2T, A2, b2, xtok, xsum);

  // 3) LN3 stats, score column, G3 -> xproj + xprojT (xtok dead; xprojT overwrites it)
  rowstats512_f16<<<NTOK / 4, 256, 0, stream>>>(xsum, meanA, rstdA);
  score_kernel<<<NTOK / 4, 256, 0, stream>>>(xsum, meanA, rstdA, g3, bl3, W3T, b3, xscore);
  g3_kernel<<<dim3(4, 512), 256, 0, stream>>>(xsum, meanA, rstdA, g3, bl3, W3T + 512, b3,
                                              xproj, xprojT);

  // 4) top-k -> Wm (f16, d_out[64,80))
  topk_kernel<<<B_, 512, 0, stream>>>(xscore, tau, Wm);

  // 5) WmT for GY
  transpose_cvt<f16><<<dim3(64, 4, B_), tb, 0, stream>>>(Wm, WmT, 128, 2048,
      (long)KSEL * SEQ_, (long)SEQ_ * KSEL);

  // 6) Z = Wm @ xproj (split-K=2), then reduce+transpose -> ZT
  gz_kernel<<<dim3(4, 2, B_), 256, 0, stream>>>(Wm, xprojT, Zpart);
  ztrans_kernel<<<dim3(16, 4, B_), tb, 0, stream>>>(Zpart, ZT);

  // 7) rbuf = xproj + Wm^T @ Z (overwrites xsum)
  gy_kernel<<<dim3(4, 16, B_), 256, 0, stream>>>(WmT, ZT, xproj, rbuf);

  // 8) LN4 stats + G4 -> out (overwrites all d_out scratch)
  rowstats512_f16<<<NTOK / 4, 256, 0, stream>>>(rbuf, meanA, rstdA);
  g4_kernel<<<dim3(4, 512), 256, 0, stream>>>(rbuf, meanA, rstdA, g4, bl4, W4T, b4, out);
}

// Round 11
// 938.633 us; speedup vs baseline: 1.0286x; 1.0286x over previous
//
#include <hip/hip_runtime.h>
#include <math.h>

#define B_   32
#define SEQ_ 2048
#define DIM_ 512
#define KSEL 128

typedef _Float16 f16;
typedef _Float16 half8 __attribute__((ext_vector_type(8)));
typedef _Float16 half4 __attribute__((ext_vector_type(4)));
typedef float floatx4 __attribute__((ext_vector_type(4)));

#define LSTR2 32   // LDS row stride in halves (64B rows)

__device__ __forceinline__ float gelu_exact(float v) {
  return 0.5f * v * (1.0f + erff(v * 0.70710678118654752440f));
}

// ======================= stats kernels =======================
__global__ __launch_bounds__(256) void rowstats512(const float* __restrict__ X,
                                                   float* __restrict__ mean,
                                                   float* __restrict__ rstd) {
  int row = blockIdx.x * 4 + (threadIdx.x >> 6);
  int l = threadIdx.x & 63;
  const float4* p = (const float4*)(X + (size_t)row * 512);
  float4 v0 = p[l * 2], v1 = p[l * 2 + 1];
  float s = v0.x + v0.y + v0.z + v0.w + v1.x + v1.y + v1.z + v1.w;
  float q = v0.x*v0.x + v0.y*v0.y + v0.z*v0.z + v0.w*v0.w
          + v1.x*v1.x + v1.y*v1.y + v1.z*v1.z + v1.w*v1.w;
#pragma unroll
  for (int off = 32; off > 0; off >>= 1) {
    s += __shfl_down(s, off);
    q += __shfl_down(q, off);
  }
  if (l == 0) {
    float m = s * (1.0f / 512.0f);
    float var = q * (1.0f / 512.0f) - m * m;
    mean[row] = m;
    rstd[row] = rsqrtf(var + 1e-5f);
  }
}

__global__ __launch_bounds__(256) void rowstats512_f16(const f16* __restrict__ X,
                                                       float* __restrict__ mean,
                                                       float* __restrict__ rstd) {
  int row = blockIdx.x * 4 + (threadIdx.x >> 6);
  int l = threadIdx.x & 63;
  half8 h = *(const half8*)(X + (size_t)row * 512 + l * 8);
  float s = 0.f, q = 0.f;
#pragma unroll
  for (int i = 0; i < 8; ++i) { float v = (float)h[i]; s += v; q += v * v; }
#pragma unroll
  for (int off = 32; off > 0; off >>= 1) {
    s += __shfl_down(s, off);
    q += __shfl_down(q, off);
  }
  if (l == 0) {
    float m = s * (1.0f / 512.0f);
    float var = q * (1.0f / 512.0f) - m * m;
    mean[row] = m;
    rstd[row] = rsqrtf(var + 1e-5f);
  }
}

__global__ __launch_bounds__(512) void colstats_part(const f16* __restrict__ xtok,
                                                     float2* __restrict__ part) {
  int b = blockIdx.x >> 3, pr = blockIdx.x & 7;
  int d = threadIdx.x;
  const f16* src = xtok + ((size_t)b * SEQ_ + (size_t)pr * 256) * 512 + d;
  float s = 0.f, q = 0.f;
#pragma unroll 4
  for (int i = 0; i < 256; ++i) {
    float v = (float)src[(size_t)i * 512];
    s += v; q += v * v;
  }
  part[(size_t)blockIdx.x * 512 + d] = make_float2(s, q);
}

__global__ __launch_bounds__(256) void colstats_fin(const float2* __restrict__ part,
                                                    float* __restrict__ mean,
                                                    float* __restrict__ rstd) {
  int idx = blockIdx.x * 256 + threadIdx.x;
  int b = idx >> 9;
  float s = 0.f, q = 0.f;
#pragma unroll
  for (int p = 0; p < 8; ++p) {
    float2 v = part[((size_t)(b * 8 + p)) * 512 + (idx & 511)];
    s += v.x; q += v.y;
  }
  float m = s * (1.0f / 2048.0f);
  mean[idx] = m;
  rstd[idx] = rsqrtf(q * (1.0f / 2048.0f) - m * m + 1e-5f);
}

// ======================= transpose / convert =======================
template <typename T>
__global__ __launch_bounds__(256) void transpose_cvt(const T* __restrict__ src,
                                                     f16* __restrict__ dst,
                                                     int R, int C, long sb, long db) {
  __shared__ float tile[32][33];
  const T* s = src + (long)blockIdx.z * sb;
  f16* d = dst + (long)blockIdx.z * db;
  int c0 = blockIdx.x * 32, r0 = blockIdx.y * 32;
  int tx = threadIdx.x, ty = threadIdx.y;
#pragma unroll
  for (int i = 0; i < 4; ++i) {
    int r = r0 + ty + i * 8, c = c0 + tx;
    if (r < R && c < C) tile[ty + i * 8][tx] = (float)s[(long)r * C + c];
  }
  __syncthreads();
#pragma unroll
  for (int i = 0; i < 4; ++i) {
    int c = c0 + ty + i * 8, r = r0 + tx;
    if (c < C && r < R) d[(long)c * R + r] = (f16)tile[tx][ty + i * 8];
  }
}

// LN2-apply + transpose: A2[b][d][s] = (xtok[b][s][d]-m2[b,d])*r2[b,d]*g2[s]+bl2[s]
__global__ __launch_bounds__(256) void trans2_kernel(const f16* __restrict__ xtok,
    const float* __restrict__ mean2, const float* __restrict__ rstd2,
    const float* __restrict__ g2, const float* __restrict__ bl2,
    f16* __restrict__ A2) {
  __shared__ float tile[32][33];
  int b = blockIdx.z;
  const f16* src = xtok + (long)b * SEQ_ * 512;
  f16* dst = A2 + (long)b * 512 * SEQ_;
  int d0 = blockIdx.x * 32, s0 = blockIdx.y * 32;
  int tx = threadIdx.x, ty = threadIdx.y;
  float m = mean2[b * 512 + d0 + tx];
  float rs = rstd2[b * 512 + d0 + tx];
#pragma unroll
  for (int i = 0; i < 4; ++i) {
    int s = s0 + ty + i * 8;
    float v = (float)src[(long)s * 512 + d0 + tx];
    tile[ty + i * 8][tx] = (v - m) * rs * g2[s] + bl2[s];
  }
  __syncthreads();
#pragma unroll
  for (int i = 0; i < 4; ++i) {
    int d = d0 + ty + i * 8, s = s0 + tx;
    dst[(long)d * SEQ_ + s] = (f16)tile[tx][ty + i * 8];
  }
}

// ======================= 128x128 GEMM core (round-4 proven structure) =======================
__device__ __forceinline__ void stage_gll(const f16* __restrict__ src, long ld,
                                          int row0, int k0, f16* S, int t) {
  int w = t >> 6, lane = t & 63;
  int r = lane >> 2, c8 = (lane & 3) * 8;
#pragma unroll
  for (int i = 0; i < 2; ++i) {
    int chunk = w * 2 + i;
    const f16* g = src + (long)(row0 + chunk * 16 + r) * ld + k0 + c8;
    f16* l = S + chunk * 16 * LSTR2;
    __builtin_amdgcn_global_load_lds(
        (const __attribute__((address_space(1))) void*)g,
        (__attribute__((address_space(3))) void*)l, 16, 0, 0);
  }
}

// stage 64 rows x 32h: exactly 1 gll/thread
__device__ __forceinline__ void stage_gll64(const f16* __restrict__ src, long ld,
                                            int k0, f16* S, int t) {
  int row = t >> 2, c8 = (t & 3) * 8;
  const f16* g = src + (long)row * ld + k0 + c8;
  f16* l = S + (t >> 6) * 16 * LSTR2;   // wave-uniform base; HW adds lane*16B
  __builtin_amdgcn_global_load_lds(
      (const __attribute__((address_space(1))) void*)g,
      (__attribute__((address_space(3))) void*)l, 16, 0, 0);
}

__device__ __forceinline__ void stage_a_ln_f32(const float* __restrict__ src, long ld,
    const float* __restrict__ mean, const float* __restrict__ rstd,
    const float* __restrict__ g, const float* __restrict__ bl,
    int row0, int k0, f16* S, int t) {
  int row = t >> 1, kc = (t & 1) * 16;
  int r = row0 + row, c = k0 + kc;
  float m = mean[r], sd = rstd[r];
  const float* p = src + (long)r * ld + c;
  float v[16], gv[16], bv[16];
#pragma unroll
  for (int i = 0; i < 4; ++i) {
    float4 q = ((const float4*)p)[i];
    v[i*4+0]=q.x; v[i*4+1]=q.y; v[i*4+2]=q.z; v[i*4+3]=q.w;
    float4 gq = ((const float4*)(g + c))[i];
    gv[i*4+0]=gq.x; gv[i*4+1]=gq.y; gv[i*4+2]=gq.z; gv[i*4+3]=gq.w;
    float4 bq = ((const float4*)(bl + c))[i];
    bv[i*4+0]=bq.x; bv[i*4+1]=bq.y; bv[i*4+2]=bq.z; bv[i*4+3]=bq.w;
  }
  half8 o0, o1;
#pragma unroll
  for (int i = 0; i < 8; ++i) {
    o0[i] = (f16)((v[i] - m) * sd * gv[i] + bv[i]);
    o1[i] = (f16)((v[i + 8] - m) * sd * gv[i + 8] + bv[i + 8]);
  }
  *(half8*)(S + row * LSTR2 + kc) = o0;
  *(half8*)(S + row * LSTR2 + kc + 8) = o1;
}

__device__ __forceinline__ void stage_a_ln_f16(const f16* __restrict__ src, long ld,
    const float* __restrict__ mean, const float* __restrict__ rstd,
    const float* __restrict__ g, const float* __restrict__ bl,
    int row0, int k0, f16* S, int t) {
  int row = t >> 1, kc = (t & 1) * 16;
  int r = row0 + row, c = k0 + kc;
  float m = mean[r], sd = rstd[r];
  const f16* p = src + (long)r * ld + c;
  half8 h0 = *(const half8*)(p);
  half8 h1 = *(const half8*)(p + 8);
  float gv[16], bv[16];
#pragma unroll
  for (int i = 0; i < 4; ++i) {
    float4 gq = ((const float4*)(g + c))[i];
    gv[i*4+0]=gq.x; gv[i*4+1]=gq.y; gv[i*4+2]=gq.z; gv[i*4+3]=gq.w;
    float4 bq = ((const float4*)(bl + c))[i];
    bv[i*4+0]=bq.x; bv[i*4+1]=bq.y; bv[i*4+2]=bq.z; bv[i*4+3]=bq.w;
  }
  half8 o0, o1;
#pragma unroll
  for (int i = 0; i < 8; ++i) {
    o0[i] = (f16)(((float)h0[i] - m) * sd * gv[i] + bv[i]);
    o1[i] = (f16)(((float)h1[i] - m) * sd * gv[i + 8] + bv[i + 8]);
  }
  *(half8*)(S + row * LSTR2 + kc) = o0;
  *(half8*)(S + row * LSTR2 + kc + 8) = o1;
}

__device__ __forceinline__ void mfma_step(const f16* As, const f16* Bs, int lane,
                                          int wr, int wc, floatx4 acc[4][4]) {
  int kc = (lane >> 4) * 8;
  int rl = lane & 15;
  half8 a[4], b[4];
#pragma unroll
  for (int mi = 0; mi < 4; ++mi)
    a[mi] = *(const half8*)(As + (wr * 64 + mi * 16 + rl) * LSTR2 + kc);
#pragma unroll
  for (int ni = 0; ni < 4; ++ni)
    b[ni] = *(const half8*)(Bs + (wc * 64 + ni * 16 + rl) * LSTR2 + kc);
#pragma unroll
  for (int mi = 0; mi < 4; ++mi)
#pragma unroll
    for (int ni = 0; ni < 4; ++ni)
      acc[mi][ni] = __builtin_amdgcn_mfma_f32_16x16x32_f16(a[mi], b[ni], acc[mi][ni], 0, 0, 0);
}

// narrow variant: 128(M) x 64(N), wave-tile 64x32, acc[4][2]
__device__ __forceinline__ void mfma_step_n64(const f16* As, const f16* Bs, int lane,
                                              int wr, int wc, floatx4 acc[4][2]) {
  int kc = (lane >> 4) * 8;
  int rl = lane & 15;
  half8 a[4], b[2];
#pragma unroll
  for (int mi = 0; mi < 4; ++mi)
    a[mi] = *(const half8*)(As + (wr * 64 + mi * 16 + rl) * LSTR2 + kc);
#pragma unroll
  for (int ni = 0; ni < 2; ++ni)
    b[ni] = *(const half8*)(Bs + (wc * 32 + ni * 16 + rl) * LSTR2 + kc);
#pragma unroll
  for (int mi = 0; mi < 4; ++mi)
#pragma unroll
    for (int ni = 0; ni < 2; ++ni)
      acc[mi][ni] = __builtin_amdgcn_mfma_f32_16x16x32_f16(a[mi], b[ni], acc[mi][ni], 0, 0, 0);
}

#define GEMM_PROLOG \
  __shared__ __attribute__((aligned(16))) f16 As[128 * LSTR2]; \
  __shared__ __attribute__((aligned(16))) f16 Bs[128 * LSTR2]; \
  int t = threadIdx.x; \
  int lane = t & 63, w = t >> 6, wr = w >> 1, wc = w & 1; \
  floatx4 acc[4][4]; \
  _Pragma("unroll") for (int mi = 0; mi < 4; ++mi) \
  _Pragma("unroll") for (int ni = 0; ni < 4; ++ni) acc[mi][ni] = (floatx4){0.f,0.f,0.f,0.f};

#define GEMM_PROLOG_N64 \
  __shared__ __attribute__((aligned(16))) f16 As[128 * LSTR2]; \
  __shared__ __attribute__((aligned(16))) f16 Bs[64 * LSTR2]; \
  int t = threadIdx.x; \
  int lane = t & 63, w = t >> 6, wr = w >> 1, wc = w & 1; \
  int rl = lane & 15, sl = lane >> 4; \
  floatx4 acc[4][2]; \
  _Pragma("unroll") for (int mi = 0; mi < 4; ++mi) \
  _Pragma("unroll") for (int ni = 0; ni < 2; ++ni) acc[mi][ni] = (floatx4){0.f,0.f,0.f,0.f};

// ---- G1: x_tok = gelu(ln1(x)@W1 + b1). grid (4, 512) ----
__global__ __launch_bounds__(256) void g1_kernel(const float* __restrict__ x,
    const float* __restrict__ mean, const float* __restrict__ rstd,
    const float* __restrict__ g1, const float* __restrict__ bl1,
    const f16* __restrict__ W1T, const float* __restrict__ b1,
    f16* __restrict__ xtok) {
  GEMM_PROLOG
  int m0 = blockIdx.y * 128, n0 = blockIdx.x * 128;
  for (int k0 = 0; k0 < 512; k0 += 32) {
    stage_a_ln_f32(x, 512, mean, rstd, g1, bl1, m0, k0, As, t);
    stage_gll(W1T, 512, n0, k0, Bs, t);
    __syncthreads();
    mfma_step(As, Bs, lane, wr, wc, acc);
    __syncthreads();
  }
#pragma unroll
  for (int mi = 0; mi < 4; ++mi)
#pragma unroll
    for (int ni = 0; ni < 4; ++ni) {
      int c = n0 + wc * 64 + ni * 16 + (lane & 15);
      float bias = b1[c];
      int r0 = m0 + wr * 64 + mi * 16 + (lane >> 4) * 4;
#pragma unroll
      for (int j = 0; j < 4; ++j)
        xtok[(long)(r0 + j) * 512 + c] = (f16)gelu_exact(acc[mi][ni][j] + bias);
    }
}

// ---- G2 v2: tile 128(s') x 64(d), grid (8, 16, 32) = 4096 blocks ----
__global__ __launch_bounds__(256) void g2_kernel(const f16* __restrict__ W2T,
    const f16* __restrict__ A2, const float* __restrict__ b2,
    const f16* __restrict__ xtok, f16* __restrict__ xsum) {
  GEMM_PROLOG_N64
  int b = blockIdx.z;
  int m0 = blockIdx.y * 128, n0 = blockIdx.x * 64;
  const f16* Am = W2T + (long)m0 * SEQ_;
  const f16* Bm = A2 + (long)b * 512 * SEQ_ + (long)n0 * SEQ_;
  const f16* xtb = xtok + (long)b * SEQ_ * 512;
  f16* xsb = xsum + (long)b * SEQ_ * 512;
  for (int k0 = 0; k0 < SEQ_; k0 += 32) {
    stage_gll(Am, SEQ_, 0, k0, As, t);
    stage_gll64(Bm, SEQ_, k0, Bs, t);
    __syncthreads();
    mfma_step_n64(As, Bs, lane, wr, wc, acc);
    __syncthreads();
  }
#pragma unroll
  for (int mi = 0; mi < 4; ++mi)
#pragma unroll
    for (int ni = 0; ni < 2; ++ni) {
      int cc = n0 + wc * 32 + ni * 16 + rl;
      int r0 = m0 + wr * 64 + mi * 16 + sl * 4;
#pragma unroll
      for (int j = 0; j < 4; ++j) {
        int r = r0 + j;
        long idx = (long)r * 512 + cc;
        float v = gelu_exact(acc[mi][ni][j] + b2[r]);
        xsb[idx] = (f16)((float)xtb[idx] + v);
      }
    }
}

// ---- G3: xproj = ln3(xsum)@W3[:,1:] + b3[1:], dual-write xprojT. grid (4,512) ----
__global__ __launch_bounds__(256) void g3_kernel(const f16* __restrict__ xsum,
    const float* __restrict__ mean, const float* __restrict__ rstd,
    const float* __restrict__ g3, const float* __restrict__ bl3,
    const f16* __restrict__ BT /* = W3T + 512 */, const float* __restrict__ b3,
    f16* __restrict__ xproj, f16* __restrict__ xprojT) {
  GEMM_PROLOG
  int m0 = blockIdx.y * 128, n0 = blockIdx.x * 128;
  for (int k0 = 0; k0 < 512; k0 += 32) {
    stage_a_ln_f16(xsum, 512, mean, rstd, g3, bl3, m0, k0, As, t);
    stage_gll(BT, 512, n0, k0, Bs, t);
    __syncthreads();
    mfma_step(As, Bs, lane, wr, wc, acc);
    __syncthreads();
  }
#pragma unroll
  for (int mi = 0; mi < 4; ++mi)
#pragma unroll
    for (int ni = 0; ni < 4; ++ni) {
      int c = n0 + wc * 64 + ni * 16 + (lane & 15);
      float bias = b3[c + 1];
      int r0 = m0 + wr * 64 + mi * 16 + (lane >> 4) * 4;
      half4 xp;
#pragma unroll
      for (int j = 0; j < 4; ++j) {
        f16 v = (f16)(acc[mi][ni][j] + bias);
        xproj[(long)(r0 + j) * 512 + c] = v;
        xp[j] = v;
      }
      long bb = r0 >> 11;
      long rloc = r0 & 2047;
      *(half4*)(xprojT + (bb * 512 + c) * SEQ_ + rloc) = xp;
    }
}

// ---- score ----
__global__ __launch_bounds__(256) void score_kernel(const f16* __restrict__ xsum,
    const float* __restrict__ mean, const float* __restrict__ rstd,
    const float* __restrict__ g3, const float* __restrict__ bl3,
    const f16* __restrict__ w3c, const float* __restrict__ b3,
    float* __restrict__ xscore) {
  int row = blockIdx.x * 4 + (threadIdx.x >> 6);
  int l = threadIdx.x & 63;
  float m = mean[row], sd = rstd[row];
  half8 h = *(const half8*)(xsum + (long)row * 512 + l * 8);
  half8 wv = *(const half8*)(w3c + l * 8);
  float acc = 0.f;
#pragma unroll
  for (int i = 0; i < 8; ++i) {
    int d = l * 8 + i;
    float v = ((float)h[i] - m) * sd * g3[d] + bl3[d];
    acc += v * (float)wv[i];
  }
#pragma unroll
  for (int off = 32; off > 0; off >>= 1) acc += __shfl_down(acc, off);
  if (l == 0) xscore[row] = acc + b3[0];
}

// ---- diff_topk: 512 threads, 4 elems/lane, single barrier/iter ----
__global__ __launch_bounds__(512) void topk_kernel(const float* __restrict__ xscore,
                                                   const float* __restrict__ tau,
                                                   f16* __restrict__ Wm) {
  int b = blockIdx.x, t = threadIdx.x;
  __shared__ float red[2][8];
  float tv = fminf(fmaxf(tau[0], -2.0f), 5.0f);
  float temp = 1.0f / (1.0f + expf(-tv));
  float it = 1.0f / temp;
  float c[4];
  const float* xs = xscore + (size_t)b * SEQ_;
  {
    float4 v = *(const float4*)(xs + t * 4);
    c[0] = v.x; c[1] = v.y; c[2] = v.z; c[3] = v.w;
  }
  int l = t & 63, wid = t >> 6;
  for (int k = 0; k < KSEL; ++k) {
    float e[4];
    float p = 0.f;
#pragma unroll
    for (int i = 0; i < 4; ++i) { e[i] = expf(c[i] * it); p += e[i]; }
#pragma unroll
    for (int off = 32; off > 0; off >>= 1) p += __shfl_down(p, off);
    if (l == 0) red[k & 1][wid] = p;
    __syncthreads();
    float S = 0.f;
#pragma unroll
    for (int q = 0; q < 8; ++q) S += red[k & 1][q];
    float iS = 1.0f / S;
    half4 h;
    float a[4];
#pragma unroll
    for (int i = 0; i < 4; ++i) { a[i] = e[i] * iS; h[i] = (f16)a[i]; }
    *(half4*)(Wm + ((size_t)b * KSEL + k) * SEQ_ + t * 4) = h;
#pragma unroll
    for (int i = 0; i < 4; ++i) c[i] += logf(fmaxf(1.0f - a[i], 1e-6f));
  }
}

// ---- GZ v2 (split-K=4): tile 128(kq) x 64(d). grid (8, 4, 32) = 1024 blocks ----
__global__ __launch_bounds__(256) void gz_kernel(const f16* __restrict__ Wm,
    const f16* __restrict__ xprojT, float* __restrict__ Zpart) {
  GEMM_PROLOG_N64
  int b = blockIdx.z, kc = blockIdx.y;
  int n0 = blockIdx.x * 64;
  const f16* Am = Wm + (long)b * KSEL * SEQ_;
  const f16* Bm = xprojT + (long)b * 512 * SEQ_ + (long)n0 * SEQ_;
  float* Zb = Zpart + ((long)b * 4 + kc) * KSEL * 512;
  int kbeg = kc * 512, kend = kbeg + 512;
  for (int k0 = kbeg; k0 < kend; k0 += 32) {
    stage_gll(Am, SEQ_, 0, k0, As, t);
    stage_gll64(Bm, SEQ_, k0, Bs, t);
    __syncthreads();
    mfma_step_n64(As, Bs, lane, wr, wc, acc);
    __syncthreads();
  }
#pragma unroll
  for (int mi = 0; mi < 4; ++mi)
#pragma unroll
    for (int ni = 0; ni < 2; ++ni) {
      int cc = n0 + wc * 32 + ni * 16 + rl;
      int r0 = wr * 64 + mi * 16 + sl * 4;
#pragma unroll
      for (int j = 0; j < 4; ++j)
        Zb[(long)(r0 + j) * 512 + cc] = acc[mi][ni][j];
    }
}

// ---- reduce split-K(4) + transpose -> ZT ----
__global__ __launch_bounds__(256) void ztrans_kernel(const float* __restrict__ Zpart,
                                                     f16* __restrict__ ZT) {
  __shared__ float tile[32][33];
  int b = blockIdx.z;
  int c0 = blockIdx.x * 32, r0 = blockIdx.y * 32;
  int tx = threadIdx.x, ty = threadIdx.y;
  const float* p0 = Zpart + ((long)b * 4 + 0) * KSEL * 512;
  const float* p1 = Zpart + ((long)b * 4 + 1) * KSEL * 512;
  const float* p2 = Zpart + ((long)b * 4 + 2) * KSEL * 512;
  const float* p3 = Zpart + ((long)b * 4 + 3) * KSEL * 512;
#pragma unroll
  for (int i = 0; i < 4; ++i) {
    int r = r0 + ty + i * 8, c = c0 + tx;
    long idx = (long)r * 512 + c;
    tile[ty + i * 8][tx] = (p0[idx] + p1[idx]) + (p2[idx] + p3[idx]);
  }
  __syncthreads();
  f16* d = ZT + (long)b * 512 * KSEL;
#pragma unroll
  for (int i = 0; i < 4; ++i) {
    int c = c0 + ty + i * 8, r = r0 + tx;
    d[(long)c * KSEL + r] = (f16)tile[tx][ty + i * 8];
  }
}

// ---- GY: rbuf = xproj + Wm^T @ Z. grid (4, 16, 32), K=128 ----
__global__ __launch_bounds__(256) void gy_kernel(const f16* __restrict__ WmT,
    const f16* __restrict__ ZT, const f16* __restrict__ xproj,
    f16* __restrict__ rbuf) {
  GEMM_PROLOG
  int b = blockIdx.z;
  int m0 = blockIdx.y * 128, n0 = blockIdx.x * 128;
  const f16* A = WmT + (long)b * SEQ_ * KSEL;
  const f16* BT = ZT + (long)b * 512 * KSEL;
  const f16* xpb = xproj + (long)b * SEQ_ * 512;
  f16* rb = rbuf + (long)b * SEQ_ * 512;
  for (int k0 = 0; k0 < KSEL; k0 += 32) {
    stage_gll(A, KSEL, m0, k0, As, t);
    stage_gll(BT, KSEL, n0, k0, Bs, t);
    __syncthreads();
    mfma_step(As, Bs, lane, wr, wc, acc);
    __syncthreads();
  }
#pragma unroll
  for (int mi = 0; mi < 4; ++mi)
#pragma unroll
    for (int ni = 0; ni < 4; ++ni) {
      int c = n0 + wc * 64 + ni * 16 + (lane & 15);
      int r0 = m0 + wr * 64 + mi * 16 + (lane >> 4) * 4;
#pragma unroll
      for (int j = 0; j < 4; ++j) {
        long idx = (long)(r0 + j) * 512 + c;
        rb[idx] = (f16)((float)xpb[idx] + acc[mi][ni][j]);
      }
    }
}

// ---- G4: out = ln4(rbuf)@W4 + b4 (fp32 out). grid (4, 512) ----
__global__ __launch_bounds__(256) void g4_kernel(const f16* __restrict__ rbuf,
    const float* __restrict__ mean, const float* __restrict__ rstd,
    const float* __restrict__ g4, const float* __restrict__ bl4,
    const f16* __restrict__ W4T, const float* __restrict__ b4,
    float* __restrict__ out) {
  GEMM_PROLOG
  int m0 = blockIdx.y * 128, n0 = blockIdx.x * 128;
  for (int k0 = 0; k0 < 512; k0 += 32) {
    stage_a_ln_f16(rbuf, 512, mean, rstd, g4, bl4, m0, k0, As, t);
    stage_gll(W4T, 512, n0, k0, Bs, t);
    __syncthreads();
    mfma_step(As, Bs, lane, wr, wc, acc);
    __syncthreads();
  }
#pragma unroll
  for (int mi = 0; mi < 4; ++mi)
#pragma unroll
    for (int ni = 0; ni < 4; ++ni) {
      int c = n0 + wc * 64 + ni * 16 + (lane & 15);
      float bias = b4[c];
      int r0 = m0 + wr * 64 + mi * 16 + (lane >> 4) * 4;
#pragma unroll
      for (int j = 0; j < 4; ++j)
        out[(long)(r0 + j) * 512 + c] = acc[mi][ni][j] + bias;
    }
}

// ======================= launcher =======================
extern "C" void kernel_launch(void* const* d_in, const int* in_sizes, int n_in,
                              void* d_out, int out_size, void* d_ws, size_t ws_size,
                              hipStream_t stream) {
  const float* x    = (const float*)d_in[0];
  const float* tau  = (const float*)d_in[1];
  const float* g1   = (const float*)d_in[2];
  const float* bl1  = (const float*)d_in[3];
  const float* W1   = (const float*)d_in[4];
  const float* b1   = (const float*)d_in[5];
  const float* g2   = (const float*)d_in[6];
  const float* bl2  = (const float*)d_in[7];
  const float* W2   = (const float*)d_in[8];
  const float* b2   = (const float*)d_in[9];
  const float* g3   = (const float*)d_in[10];
  const float* bl3  = (const float*)d_in[11];
  const float* W3   = (const float*)d_in[12];
  const float* b3   = (const float*)d_in[13];
  const float* g4   = (const float*)d_in[14];
  const float* bl4  = (const float*)d_in[15];
  const float* W4   = (const float*)d_in[16];
  const float* b4   = (const float*)d_in[17];
  float* out = (float*)d_out;

  const long NTOK = (long)B_ * SEQ_;  // 65536

  // ---- workspace layout ----
  char* ws = (char*)d_ws;
  f16* regA   = (f16*)(ws);                         // 64MB: A2, later xproj
  f16* regB   = (f16*)(ws + (64l << 20));           // 64MB: xsum, later rbuf
  f16* W2T    = (f16*)(ws + (144l << 20));          // 8MB
  f16* W1T    = (f16*)(ws + (152l << 20));          // 0.5MB
  f16* W3T    = (f16*)(ws + (153l << 20));          // 0.51MB
  f16* W4T    = (f16*)(ws + (154l << 20));          // 0.5MB
  float* xscore = (float*)(ws + (155l << 20));      // 0.25MB
  float* meanA  = (float*)(ws + (156l << 20));      // 0.25MB
  float* rstdA  = meanA + NTOK;                     // 0.25MB
  float* mean2  = rstdA + NTOK;                     // 64KB
  float* rstd2  = mean2 + B_ * 512;                 // 64KB
  float2* part  = (float2*)(rstd2 + B_ * 512);      // 1MB
  f16* ZT     = (f16*)(ws + (157l << 20));          // 4MB

  // ---- d_out (128MB) doubles as scratch, fully overwritten by G4 ----
  f16* xtok   = (f16*)d_out;                               // [0,64) until g2 reads it
  f16* xprojT = (f16*)d_out;                               // [0,64) written by g3 (xtok dead)
  f16* Wm     = (f16*)((char*)d_out + (64l << 20));        // [64,80)
  f16* WmT    = (f16*)((char*)d_out + (80l << 20));        // [80,96)
  float* Zpart = (float*)((char*)d_out + (96l << 20));     // [96,128) fp32, 4 partials

  f16* A2    = regA;
  f16* xsum  = regB;
  f16* xproj = regA;   // A2 dead after G2
  f16* rbuf  = regB;   // xsum dead after G3

  dim3 tb(32, 8);

  // weight transposes (f16, [n][k])
  transpose_cvt<float><<<dim3(16, 16, 1), tb, 0, stream>>>(W1, W1T, 512, 512, 0, 0);
  transpose_cvt<float><<<dim3(64, 64, 1), tb, 0, stream>>>(W2, W2T, 2048, 2048, 0, 0);
  transpose_cvt<float><<<dim3(17, 16, 1), tb, 0, stream>>>(W3, W3T, 512, 513, 0, 0);
  transpose_cvt<float><<<dim3(16, 16, 1), tb, 0, stream>>>(W4, W4T, 512, 512, 0, 0);

  // 1) LN1 stats + G1 -> xtok (f16, in d_out)
  rowstats512<<<NTOK / 4, 256, 0, stream>>>(x, meanA, rstdA);
  g1_kernel<<<dim3(4, 512), 256, 0, stream>>>(x, meanA, rstdA, g1, bl1, W1T, b1, xtok);

  // 2) LN2 stats + transposed normalize -> A2, then G2 (128x64 tiles) -> xsum
  colstats_part<<<B_ * 8, 512, 0, stream>>>(xtok, part);
  colstats_fin<<<64, 256, 0, stream>>>(part, mean2, rstd2);
  trans2_kernel<<<dim3(16, 64, B_), tb, 0, stream>>>(xtok, mean2, rstd2, g2, bl2, A2);
  g2_kernel<<<dim3(8, 16, B_), 256, 0, stream>>>(W2T, A2, b2, xtok, xsum);

  // 3) LN3 stats, score column, G3 -> xproj + xprojT (xtok dead; xprojT overwrites it)
  rowstats512_f16<<<NTOK / 4, 256, 0, stream>>>(xsum, meanA, rstdA);
  score_kernel<<<NTOK / 4, 256, 0, stream>>>(xsum, meanA, rstdA, g3, bl3, W3T, b3, xscore);
  g3_kernel<<<dim3(4, 512), 256, 0, stream>>>(xsum, meanA, rstdA, g3, bl3, W3T + 512, b3,
                                              xproj, xprojT);

  // 4) top-k -> Wm (f16, d_out[64,80))
  topk_kernel<<<B_, 512, 0, stream>>>(xscore, tau, Wm);

  // 5) WmT for GY
  transpose_cvt<f16><<<dim3(64, 4, B_), tb, 0, stream>>>(Wm, WmT, 128, 2048,
      (long)KSEL * SEQ_, (long)SEQ_ * KSEL);

  // 6) Z = Wm @ xproj (split-K=4, 128x64 tiles), then reduce+transpose -> ZT
  gz_kernel<<<dim3(8, 4, B_), 256, 0, stream>>>(Wm, xprojT, Zpart);
  ztrans_kernel<<<dim3(16, 4, B_), tb, 0, stream>>>(Zpart, ZT);

  // 7) rbuf = xproj + Wm^T @ Z (overwrites xsum)
  gy_kernel<<<dim3(4, 16, B_), 256, 0, stream>>>(WmT, ZT, xproj, rbuf);

  // 8) LN4 stats + G4 -> out (overwrites all d_out scratch)
  rowstats512_f16<<<NTOK / 4, 256, 0, stream>>>(rbuf, meanA, rstdA);
  g4_kernel<<<dim3(4, 512), 256, 0, stream>>>(rbuf, meanA, rstdA, g4, bl4, W4T, b4, out);
}

// Round 12
// 823.957 us; speedup vs baseline: 1.1718x; 1.1392x over previous
//
#include <hip/hip_runtime.h>
#include <math.h>

#define B_   32
#define SEQ_ 2048
#define DIM_ 512
#define KSEL 128

typedef _Float16 f16;
typedef _Float16 half8 __attribute__((ext_vector_type(8)));
typedef _Float16 half4 __attribute__((ext_vector_type(4)));
typedef float floatx4 __attribute__((ext_vector_type(4)));

#define LSTR2 32   // LDS row stride in halves (64B rows)

__device__ __forceinline__ float gelu_exact(float v) {
  return 0.5f * v * (1.0f + erff(v * 0.70710678118654752440f));
}

// ======================= fused LN pre-passes =======================
// one wave per 512-length row: stats via shfl_xor butterfly, then normalized
// f16 output with gamma/beta applied. Replaces separate rowstats + in-loop LN.
__global__ __launch_bounds__(256) void ln_fuse_f32(const float* __restrict__ X,
    const float* __restrict__ g, const float* __restrict__ bl,
    f16* __restrict__ Y) {
  int row = blockIdx.x * 4 + (threadIdx.x >> 6);
  int l = threadIdx.x & 63;
  const float4* p = (const float4*)(X + (size_t)row * 512);
  float4 v0 = p[l * 2], v1 = p[l * 2 + 1];
  float s = v0.x + v0.y + v0.z + v0.w + v1.x + v1.y + v1.z + v1.w;
  float q = v0.x*v0.x + v0.y*v0.y + v0.z*v0.z + v0.w*v0.w
          + v1.x*v1.x + v1.y*v1.y + v1.z*v1.z + v1.w*v1.w;
#pragma unroll
  for (int off = 32; off > 0; off >>= 1) {
    s += __shfl_xor(s, off);
    q += __shfl_xor(q, off);
  }
  float m = s * (1.0f / 512.0f);
  float sd = rsqrtf(q * (1.0f / 512.0f) - m * m + 1e-5f);
  float4 g0 = ((const float4*)(g + l * 8))[0];
  float4 g1v = ((const float4*)(g + l * 8))[1];
  float4 b0 = ((const float4*)(bl + l * 8))[0];
  float4 b1v = ((const float4*)(bl + l * 8))[1];
  half8 o;
  o[0] = (f16)((v0.x - m) * sd * g0.x + b0.x);
  o[1] = (f16)((v0.y - m) * sd * g0.y + b0.y);
  o[2] = (f16)((v0.z - m) * sd * g0.z + b0.z);
  o[3] = (f16)((v0.w - m) * sd * g0.w + b0.w);
  o[4] = (f16)((v1.x - m) * sd * g1v.x + b1v.x);
  o[5] = (f16)((v1.y - m) * sd * g1v.y + b1v.y);
  o[6] = (f16)((v1.z - m) * sd * g1v.z + b1v.z);
  o[7] = (f16)((v1.w - m) * sd * g1v.w + b1v.w);
  *(half8*)(Y + (size_t)row * 512 + l * 8) = o;
}

__global__ __launch_bounds__(256) void ln_fuse_f16(const f16* __restrict__ X,
    const float* __restrict__ g, const float* __restrict__ bl,
    f16* __restrict__ Y) {
  int row = blockIdx.x * 4 + (threadIdx.x >> 6);
  int l = threadIdx.x & 63;
  half8 h = *(const half8*)(X + (size_t)row * 512 + l * 8);
  float v[8];
  float s = 0.f, q = 0.f;
#pragma unroll
  for (int i = 0; i < 8; ++i) { v[i] = (float)h[i]; s += v[i]; q += v[i] * v[i]; }
#pragma unroll
  for (int off = 32; off > 0; off >>= 1) {
    s += __shfl_xor(s, off);
    q += __shfl_xor(q, off);
  }
  float m = s * (1.0f / 512.0f);
  float sd = rsqrtf(q * (1.0f / 512.0f) - m * m + 1e-5f);
  float4 g0 = ((const float4*)(g + l * 8))[0];
  float4 g1v = ((const float4*)(g + l * 8))[1];
  float4 b0 = ((const float4*)(bl + l * 8))[0];
  float4 b1v = ((const float4*)(bl + l * 8))[1];
  half8 o;
  o[0] = (f16)((v[0] - m) * sd * g0.x + b0.x);
  o[1] = (f16)((v[1] - m) * sd * g0.y + b0.y);
  o[2] = (f16)((v[2] - m) * sd * g0.z + b0.z);
  o[3] = (f16)((v[3] - m) * sd * g0.w + b0.w);
  o[4] = (f16)((v[4] - m) * sd * g1v.x + b1v.x);
  o[5] = (f16)((v[5] - m) * sd * g1v.y + b1v.y);
  o[6] = (f16)((v[6] - m) * sd * g1v.z + b1v.z);
  o[7] = (f16)((v[7] - m) * sd * g1v.w + b1v.w);
  *(half8*)(Y + (size_t)row * 512 + l * 8) = o;
}

// ======================= stats kernels (LN2/LN3 only) =======================
__global__ __launch_bounds__(256) void rowstats512_f16(const f16* __restrict__ X,
                                                       float* __restrict__ mean,
                                                       float* __restrict__ rstd) {
  int row = blockIdx.x * 4 + (threadIdx.x >> 6);
  int l = threadIdx.x & 63;
  half8 h = *(const half8*)(X + (size_t)row * 512 + l * 8);
  float s = 0.f, q = 0.f;
#pragma unroll
  for (int i = 0; i < 8; ++i) { float v = (float)h[i]; s += v; q += v * v; }
#pragma unroll
  for (int off = 32; off > 0; off >>= 1) {
    s += __shfl_down(s, off);
    q += __shfl_down(q, off);
  }
  if (l == 0) {
    float m = s * (1.0f / 512.0f);
    float var = q * (1.0f / 512.0f) - m * m;
    mean[row] = m;
    rstd[row] = rsqrtf(var + 1e-5f);
  }
}

__global__ __launch_bounds__(512) void colstats_part(const f16* __restrict__ xtok,
                                                     float2* __restrict__ part) {
  int b = blockIdx.x >> 3, pr = blockIdx.x & 7;
  int d = threadIdx.x;
  const f16* src = xtok + ((size_t)b * SEQ_ + (size_t)pr * 256) * 512 + d;
  float s = 0.f, q = 0.f;
#pragma unroll 4
  for (int i = 0; i < 256; ++i) {
    float v = (float)src[(size_t)i * 512];
    s += v; q += v * v;
  }
  part[(size_t)blockIdx.x * 512 + d] = make_float2(s, q);
}

__global__ __launch_bounds__(256) void colstats_fin(const float2* __restrict__ part,
                                                    float* __restrict__ mean,
                                                    float* __restrict__ rstd) {
  int idx = blockIdx.x * 256 + threadIdx.x;
  int b = idx >> 9;
  float s = 0.f, q = 0.f;
#pragma unroll
  for (int p = 0; p < 8; ++p) {
    float2 v = part[((size_t)(b * 8 + p)) * 512 + (idx & 511)];
    s += v.x; q += v.y;
  }
  float m = s * (1.0f / 2048.0f);
  mean[idx] = m;
  rstd[idx] = rsqrtf(q * (1.0f / 2048.0f) - m * m + 1e-5f);
}

// ======================= transpose / convert =======================
template <typename T>
__global__ __launch_bounds__(256) void transpose_cvt(const T* __restrict__ src,
                                                     f16* __restrict__ dst,
                                                     int R, int C, long sb, long db) {
  __shared__ float tile[32][33];
  const T* s = src + (long)blockIdx.z * sb;
  f16* d = dst + (long)blockIdx.z * db;
  int c0 = blockIdx.x * 32, r0 = blockIdx.y * 32;
  int tx = threadIdx.x, ty = threadIdx.y;
#pragma unroll
  for (int i = 0; i < 4; ++i) {
    int r = r0 + ty + i * 8, c = c0 + tx;
    if (r < R && c < C) tile[ty + i * 8][tx] = (float)s[(long)r * C + c];
  }
  __syncthreads();
#pragma unroll
  for (int i = 0; i < 4; ++i) {
    int c = c0 + ty + i * 8, r = r0 + tx;
    if (c < C && r < R) d[(long)c * R + r] = (f16)tile[tx][ty + i * 8];
  }
}

// LN2-apply + transpose: A2[b][d][s] = (xtok[b][s][d]-m2[b,d])*r2[b,d]*g2[s]+bl2[s]
__global__ __launch_bounds__(256) void trans2_kernel(const f16* __restrict__ xtok,
    const float* __restrict__ mean2, const float* __restrict__ rstd2,
    const float* __restrict__ g2, const float* __restrict__ bl2,
    f16* __restrict__ A2) {
  __shared__ float tile[32][33];
  int b = blockIdx.z;
  const f16* src = xtok + (long)b * SEQ_ * 512;
  f16* dst = A2 + (long)b * 512 * SEQ_;
  int d0 = blockIdx.x * 32, s0 = blockIdx.y * 32;
  int tx = threadIdx.x, ty = threadIdx.y;
  float m = mean2[b * 512 + d0 + tx];
  float rs = rstd2[b * 512 + d0 + tx];
#pragma unroll
  for (int i = 0; i < 4; ++i) {
    int s = s0 + ty + i * 8;
    float v = (float)src[(long)s * 512 + d0 + tx];
    tile[ty + i * 8][tx] = (v - m) * rs * g2[s] + bl2[s];
  }
  __syncthreads();
#pragma unroll
  for (int i = 0; i < 4; ++i) {
    int d = d0 + ty + i * 8, s = s0 + tx;
    dst[(long)d * SEQ_ + s] = (f16)tile[tx][ty + i * 8];
  }
}

// ======================= 128x128 GEMM core (2-phase, round-4 proven) =======================
__device__ __forceinline__ void stage_gll(const f16* __restrict__ src, long ld,
                                          int row0, int k0, f16* S, int t) {
  int w = t >> 6, lane = t & 63;
  int r = lane >> 2, c8 = (lane & 3) * 8;
#pragma unroll
  for (int i = 0; i < 2; ++i) {
    int chunk = w * 2 + i;
    const f16* g = src + (long)(row0 + chunk * 16 + r) * ld + k0 + c8;
    f16* l = S + chunk * 16 * LSTR2;
    __builtin_amdgcn_global_load_lds(
        (const __attribute__((address_space(1))) void*)g,
        (__attribute__((address_space(3))) void*)l, 16, 0, 0);
  }
}

__device__ __forceinline__ void stage_a_ln_f16(const f16* __restrict__ src, long ld,
    const float* __restrict__ mean, const float* __restrict__ rstd,
    const float* __restrict__ g, const float* __restrict__ bl,
    int row0, int k0, f16* S, int t) {
  int row = t >> 1, kc = (t & 1) * 16;
  int r = row0 + row, c = k0 + kc;
  float m = mean[r], sd = rstd[r];
  const f16* p = src + (long)r * ld + c;
  half8 h0 = *(const half8*)(p);
  half8 h1 = *(const half8*)(p + 8);
  float gv[16], bv[16];
#pragma unroll
  for (int i = 0; i < 4; ++i) {
    float4 gq = ((const float4*)(g + c))[i];
    gv[i*4+0]=gq.x; gv[i*4+1]=gq.y; gv[i*4+2]=gq.z; gv[i*4+3]=gq.w;
    float4 bq = ((const float4*)(bl + c))[i];
    bv[i*4+0]=bq.x; bv[i*4+1]=bq.y; bv[i*4+2]=bq.z; bv[i*4+3]=bq.w;
  }
  half8 o0, o1;
#pragma unroll
  for (int i = 0; i < 8; ++i) {
    o0[i] = (f16)(((float)h0[i] - m) * sd * gv[i] + bv[i]);
    o1[i] = (f16)(((float)h1[i] - m) * sd * gv[i + 8] + bv[i + 8]);
  }
  *(half8*)(S + row * LSTR2 + kc) = o0;
  *(half8*)(S + row * LSTR2 + kc + 8) = o1;
}

__device__ __forceinline__ void mfma_step(const f16* As, const f16* Bs, int lane,
                                          int wr, int wc, floatx4 acc[4][4]) {
  int kc = (lane >> 4) * 8;
  int rl = lane & 15;
  half8 a[4], b[4];
#pragma unroll
  for (int mi = 0; mi < 4; ++mi)
    a[mi] = *(const half8*)(As + (wr * 64 + mi * 16 + rl) * LSTR2 + kc);
#pragma unroll
  for (int ni = 0; ni < 4; ++ni)
    b[ni] = *(const half8*)(Bs + (wc * 64 + ni * 16 + rl) * LSTR2 + kc);
#pragma unroll
  for (int mi = 0; mi < 4; ++mi)
#pragma unroll
    for (int ni = 0; ni < 4; ++ni)
      acc[mi][ni] = __builtin_amdgcn_mfma_f32_16x16x32_f16(a[mi], b[ni], acc[mi][ni], 0, 0, 0);
}

#define GEMM_PROLOG \
  __shared__ __attribute__((aligned(16))) f16 As[128 * LSTR2]; \
  __shared__ __attribute__((aligned(16))) f16 Bs[128 * LSTR2]; \
  int t = threadIdx.x; \
  int lane = t & 63, w = t >> 6, wr = w >> 1, wc = w & 1; \
  floatx4 acc[4][4]; \
  _Pragma("unroll") for (int mi = 0; mi < 4; ++mi) \
  _Pragma("unroll") for (int ni = 0; ni < 4; ++ni) acc[mi][ni] = (floatx4){0.f,0.f,0.f,0.f};

// ---- G1: x_tok = gelu(xln1 @ W1 + b1), pure-f16 gll GEMM. grid (4, 512) ----
__global__ __launch_bounds__(256) void g1_kernel(const f16* __restrict__ xln1,
    const f16* __restrict__ W1T, const float* __restrict__ b1,
    f16* __restrict__ xtok) {
  GEMM_PROLOG
  int m0 = blockIdx.y * 128, n0 = blockIdx.x * 128;
  for (int k0 = 0; k0 < 512; k0 += 32) {
    stage_gll(xln1, 512, m0, k0, As, t);
    stage_gll(W1T, 512, n0, k0, Bs, t);
    __syncthreads();
    mfma_step(As, Bs, lane, wr, wc, acc);
    __syncthreads();
  }
#pragma unroll
  for (int mi = 0; mi < 4; ++mi)
#pragma unroll
    for (int ni = 0; ni < 4; ++ni) {
      int c = n0 + wc * 64 + ni * 16 + (lane & 15);
      float bias = b1[c];
      int r0 = m0 + wr * 64 + mi * 16 + (lane >> 4) * 4;
#pragma unroll
      for (int j = 0; j < 4; ++j)
        xtok[(long)(r0 + j) * 512 + c] = (f16)gelu_exact(acc[mi][ni][j] + bias);
    }
}

// ======================= G2: 256x256 counted-vmcnt half-tile ring (round-9) =======================
__device__ __forceinline__ void stage_half(const f16* __restrict__ srcbase, long ld,
                                           f16* dst, int tid) {
#pragma unroll
  for (int q = 0; q < 2; ++q) {
    int row = q * 128 + (tid >> 2);
    int slot = (tid & 3) ^ ((row >> 1) & 3);
    const f16* g = srcbase + (long)row * ld + slot * 8;
    f16* lp = dst + (long)(q * 128 + (tid >> 6) * 16) * 32;  // wave-uniform; HW adds lane*16B
    __builtin_amdgcn_global_load_lds(
        (const __attribute__((address_space(1))) void*)g,
        (__attribute__((address_space(3))) void*)lp, 16, 0, 0);
  }
}

__device__ __forceinline__ half8 frag32(const f16* buf, int row, int sl) {
  return *(const half8*)(buf + (long)row * 32 + ((sl ^ ((row >> 1) & 3)) << 3));
}

#define BAR() __builtin_amdgcn_s_barrier()
#define WAITBAR4() do { asm volatile("s_waitcnt vmcnt(4)" ::: "memory"); \
                        __builtin_amdgcn_s_barrier(); } while (0)

// grid (2, 32, 8): x = n-tile (d), y = batch, z = m-tile (s') slowest so the
// 64 consecutive blocks sharing one W2T panel land on one XCD chunk.
__global__ __launch_bounds__(512, 2) void g2_8p(const f16* __restrict__ W2T,
    const f16* __restrict__ A2, const float* __restrict__ b2,
    const f16* __restrict__ xtok, f16* __restrict__ xsum) {
  __shared__ __attribute__((aligned(16))) f16 Ah[2][2][256 * 32];
  __shared__ __attribute__((aligned(16))) f16 Bh[2][2][256 * 32];
  int tid = threadIdx.x;
  int l = tid & 63, w = tid >> 6;
  int wr = w >> 2, wc = w & 3;          // 2M x 4N wave grid
  int rl = l & 15, sl = l >> 4;
  int b = blockIdx.y;
  int m0 = blockIdx.z * 256;            // s' base
  int n0 = blockIdx.x * 256;            // d base
  const f16* Am = W2T + (long)m0 * SEQ_;
  const f16* Bm = A2 + (long)b * 512 * SEQ_ + (long)n0 * SEQ_;
  const f16* xtb = xtok + (long)b * SEQ_ * 512;
  f16* xsb = xsum + (long)b * SEQ_ * 512;

  floatx4 acc[8][4];
#pragma unroll
  for (int mf = 0; mf < 8; ++mf)
#pragma unroll
    for (int nf = 0; nf < 4; ++nf) acc[mf][nf] = (floatx4){0.f, 0.f, 0.f, 0.f};

  half8 afr[4], bfr[4];

#define STAGE(base, tile, kk, dstbuf) \
  stage_half(base + (long)((tile) & 31) * 64 + (kk) * 32, SEQ_, dstbuf, tid)

#define READ_B(d, kk) \
  _Pragma("unroll") for (int nf = 0; nf < 4; ++nf) \
    bfr[nf] = frag32(Bh[d][kk], wc * 64 + nf * 16 + rl, sl);

#define READ_A(d, kk, mb) \
  _Pragma("unroll") for (int mi = 0; mi < 4; ++mi) \
    afr[mi] = frag32(Ah[d][kk], wr * 128 + ((mb) + mi) * 16 + rl, sl);

#define MFMA16(mb) \
  __builtin_amdgcn_s_setprio(1); \
  _Pragma("unroll") for (int mi = 0; mi < 4; ++mi) \
  _Pragma("unroll") for (int nf = 0; nf < 4; ++nf) \
    acc[(mb) + mi][nf] = __builtin_amdgcn_mfma_f32_16x16x32_f16(afr[mi], bfr[nf], acc[(mb) + mi][nf], 0, 0, 0); \
  __builtin_amdgcn_s_setprio(0);

  // ---- prologue: tile 0 fully + tile 1 k-lo halves; hard drain
  STAGE(Am, 0, 0, Ah[0][0]); STAGE(Am, 0, 1, Ah[0][1]);
  STAGE(Bm, 0, 0, Bh[0][0]); STAGE(Bm, 0, 1, Bh[0][1]);
  STAGE(Am, 1, 0, Ah[1][0]); STAGE(Bm, 1, 0, Bh[1][0]);
  asm volatile("s_waitcnt vmcnt(0)" ::: "memory");
  __builtin_amdgcn_s_barrier();

  for (int i = 0; i < 16; ++i) {
    STAGE(Am, 2 * i + 1, 1, Ah[1][1]);
    READ_B(0, 0); READ_A(0, 0, 0);
    BAR(); MFMA16(0); BAR();
    STAGE(Bm, 2 * i + 1, 1, Bh[1][1]);
    READ_A(0, 0, 4);
    BAR(); MFMA16(4); BAR();
    STAGE(Am, 2 * i + 2, 0, Ah[0][0]);
    READ_B(0, 1); READ_A(0, 1, 0);
    BAR(); MFMA16(0); BAR();
    STAGE(Bm, 2 * i + 2, 0, Bh[0][0]);
    READ_A(0, 1, 4);
    BAR(); MFMA16(4); WAITBAR4();
    STAGE(Am, 2 * i + 2, 1, Ah[0][1]);
    READ_B(1, 0); READ_A(1, 0, 0);
    BAR(); MFMA16(0); BAR();
    STAGE(Bm, 2 * i + 2, 1, Bh[0][1]);
    READ_A(1, 0, 4);
    BAR(); MFMA16(4); BAR();
    STAGE(Am, 2 * i + 3, 0, Ah[1][0]);
    READ_B(1, 1); READ_A(1, 1, 0);
    BAR(); MFMA16(0); BAR();
    STAGE(Bm, 2 * i + 3, 0, Bh[1][0]);
    READ_A(1, 1, 4);
    BAR(); MFMA16(4); WAITBAR4();
  }

  // ---- epilogue: xsum[s',d] = xtok[s',d] + gelu(acc + b2[s'])
#pragma unroll
  for (int mf = 0; mf < 8; ++mf) {
    int rbase = m0 + wr * 128 + mf * 16 + sl * 4;
#pragma unroll
    for (int j = 0; j < 4; ++j) {
      int r = rbase + j;
      float bias = b2[r];
      long rowoff = (long)r * 512;
#pragma unroll
      for (int nf = 0; nf < 4; ++nf) {
        int cc = n0 + wc * 64 + nf * 16 + rl;
        float v = gelu_exact(acc[mf][nf][j] + bias);
        xsb[rowoff + cc] = (f16)((float)xtb[rowoff + cc] + v);
      }
    }
  }
#undef STAGE
#undef READ_B
#undef READ_A
#undef MFMA16
}

// ---- G3: xproj + packed xprojT dual-write ----
__global__ __launch_bounds__(256) void g3_kernel(const f16* __restrict__ xsum,
    const float* __restrict__ mean, const float* __restrict__ rstd,
    const float* __restrict__ g3, const float* __restrict__ bl3,
    const f16* __restrict__ BT /* = W3T + 512 */, const float* __restrict__ b3,
    f16* __restrict__ xproj, f16* __restrict__ xprojT) {
  GEMM_PROLOG
  int m0 = blockIdx.y * 128, n0 = blockIdx.x * 128;
  for (int k0 = 0; k0 < 512; k0 += 32) {
    stage_a_ln_f16(xsum, 512, mean, rstd, g3, bl3, m0, k0, As, t);
    stage_gll(BT, 512, n0, k0, Bs, t);
    __syncthreads();
    mfma_step(As, Bs, lane, wr, wc, acc);
    __syncthreads();
  }
#pragma unroll
  for (int mi = 0; mi < 4; ++mi)
#pragma unroll
    for (int ni = 0; ni < 4; ++ni) {
      int c = n0 + wc * 64 + ni * 16 + (lane & 15);
      float bias = b3[c + 1];
      int r0 = m0 + wr * 64 + mi * 16 + (lane >> 4) * 4;
      half4 xp;
#pragma unroll
      for (int j = 0; j < 4; ++j) {
        f16 v = (f16)(acc[mi][ni][j] + bias);
        xproj[(long)(r0 + j) * 512 + c] = v;
        xp[j] = v;
      }
      long bb = r0 >> 11;
      long rloc = r0 & 2047;
      *(half4*)(xprojT + (bb * 512 + c) * SEQ_ + rloc) = xp;
    }
}

// ---- score ----
__global__ __launch_bounds__(256) void score_kernel(const f16* __restrict__ xsum,
    const float* __restrict__ mean, const float* __restrict__ rstd,
    const float* __restrict__ g3, const float* __restrict__ bl3,
    const f16* __restrict__ w3c, const float* __restrict__ b3,
    float* __restrict__ xscore) {
  int row = blockIdx.x * 4 + (threadIdx.x >> 6);
  int l = threadIdx.x & 63;
  float m = mean[row], sd = rstd[row];
  half8 h = *(const half8*)(xsum + (long)row * 512 + l * 8);
  half8 wv = *(const half8*)(w3c + l * 8);
  float acc = 0.f;
#pragma unroll
  for (int i = 0; i < 8; ++i) {
    int d = l * 8 + i;
    float v = ((float)h[i] - m) * sd * g3[d] + bl3[d];
    acc += v * (float)wv[i];
  }
#pragma unroll
  for (int off = 32; off > 0; off >>= 1) acc += __shfl_down(acc, off);
  if (l == 0) xscore[row] = acc + b3[0];
}

// ---- diff_topk: 512 threads, 4 elems/lane, single barrier/iter ----
__global__ __launch_bounds__(512) void topk_kernel(const float* __restrict__ xscore,
                                                   const float* __restrict__ tau,
                                                   f16* __restrict__ Wm) {
  int b = blockIdx.x, t = threadIdx.x;
  __shared__ float red[2][8];
  float tv = fminf(fmaxf(tau[0], -2.0f), 5.0f);
  float temp = 1.0f / (1.0f + expf(-tv));
  float it = 1.0f / temp;
  float c[4];
  const float* xs = xscore + (size_t)b * SEQ_;
  {
    float4 v = *(const float4*)(xs + t * 4);
    c[0] = v.x; c[1] = v.y; c[2] = v.z; c[3] = v.w;
  }
  int l = t & 63, wid = t >> 6;
  for (int k = 0; k < KSEL; ++k) {
    float e[4];
    float p = 0.f;
#pragma unroll
    for (int i = 0; i < 4; ++i) { e[i] = expf(c[i] * it); p += e[i]; }
#pragma unroll
    for (int off = 32; off > 0; off >>= 1) p += __shfl_down(p, off);
    if (l == 0) red[k & 1][wid] = p;
    __syncthreads();
    float S = 0.f;
#pragma unroll
    for (int q = 0; q < 8; ++q) S += red[k & 1][q];
    float iS = 1.0f / S;
    half4 h;
    float a[4];
#pragma unroll
    for (int i = 0; i < 4; ++i) { a[i] = e[i] * iS; h[i] = (f16)a[i]; }
    *(half4*)(Wm + ((size_t)b * KSEL + k) * SEQ_ + t * 4) = h;
#pragma unroll
    for (int i = 0; i < 4; ++i) c[i] += logf(fmaxf(1.0f - a[i], 1e-6f));
  }
}

// ---- GZ (split-K=2) ----
__global__ __launch_bounds__(256) void gz_kernel(const f16* __restrict__ Wm,
    const f16* __restrict__ xprojT, float* __restrict__ Zpart) {
  GEMM_PROLOG
  int b = blockIdx.z, kc = blockIdx.y;
  int n0 = blockIdx.x * 128;
  const f16* A = Wm + (long)b * KSEL * SEQ_;
  const f16* BT = xprojT + (long)b * 512 * SEQ_;
  float* Zb = Zpart + ((long)b * 2 + kc) * KSEL * 512;
  int kbeg = kc * 1024, kend = kbeg + 1024;
  for (int k0 = kbeg; k0 < kend; k0 += 32) {
    stage_gll(A, SEQ_, 0, k0, As, t);
    stage_gll(BT, SEQ_, n0, k0, Bs, t);
    __syncthreads();
    mfma_step(As, Bs, lane, wr, wc, acc);
    __syncthreads();
  }
#pragma unroll
  for (int mi = 0; mi < 4; ++mi)
#pragma unroll
    for (int ni = 0; ni < 4; ++ni) {
      int c = n0 + wc * 64 + ni * 16 + (lane & 15);
      int r0 = wr * 64 + mi * 16 + (lane >> 4) * 4;
#pragma unroll
      for (int j = 0; j < 4; ++j)
        Zb[(long)(r0 + j) * 512 + c] = acc[mi][ni][j];
    }
}

// ---- reduce split-K + transpose -> ZT ----
__global__ __launch_bounds__(256) void ztrans_kernel(const float* __restrict__ Zpart,
                                                     f16* __restrict__ ZT) {
  __shared__ float tile[32][33];
  int b = blockIdx.z;
  int c0 = blockIdx.x * 32, r0 = blockIdx.y * 32;
  int tx = threadIdx.x, ty = threadIdx.y;
  const float* p0 = Zpart + ((long)b * 2 + 0) * KSEL * 512;
  const float* p1 = Zpart + ((long)b * 2 + 1) * KSEL * 512;
#pragma unroll
  for (int i = 0; i < 4; ++i) {
    int r = r0 + ty + i * 8, c = c0 + tx;
    tile[ty + i * 8][tx] = p0[(long)r * 512 + c] + p1[(long)r * 512 + c];
  }
  __syncthreads();
  f16* d = ZT + (long)b * 512 * KSEL;
#pragma unroll
  for (int i = 0; i < 4; ++i) {
    int c = c0 + ty + i * 8, r = r0 + tx;
    d[(long)c * KSEL + r] = (f16)tile[tx][ty + i * 8];
  }
}

// ---- GY: rbuf = xproj + Wm^T @ Z. grid (4, 16, 32), K=128 ----
__global__ __launch_bounds__(256) void gy_kernel(const f16* __restrict__ WmT,
    const f16* __restrict__ ZT, const f16* __restrict__ xproj,
    f16* __restrict__ rbuf) {
  GEMM_PROLOG
  int b = blockIdx.z;
  int m0 = blockIdx.y * 128, n0 = blockIdx.x * 128;
  const f16* A = WmT + (long)b * SEQ_ * KSEL;
  const f16* BT = ZT + (long)b * 512 * KSEL;
  const f16* xpb = xproj + (long)b * SEQ_ * 512;
  f16* rb = rbuf + (long)b * SEQ_ * 512;
  for (int k0 = 0; k0 < KSEL; k0 += 32) {
    stage_gll(A, KSEL, m0, k0, As, t);
    stage_gll(BT, KSEL, n0, k0, Bs, t);
    __syncthreads();
    mfma_step(As, Bs, lane, wr, wc, acc);
    __syncthreads();
  }
#pragma unroll
  for (int mi = 0; mi < 4; ++mi)
#pragma unroll
    for (int ni = 0; ni < 4; ++ni) {
      int c = n0 + wc * 64 + ni * 16 + (lane & 15);
      int r0 = m0 + wr * 64 + mi * 16 + (lane >> 4) * 4;
#pragma unroll
      for (int j = 0; j < 4; ++j) {
        long idx = (long)(r0 + j) * 512 + c;
        rb[idx] = (f16)((float)xpb[idx] + acc[mi][ni][j]);
      }
    }
}

// ---- G4: out = xln4 @ W4 + b4 (fp32 out), pure-f16 gll GEMM. grid (4, 512) ----
__global__ __launch_bounds__(256) void g4_kernel(const f16* __restrict__ xln4,
    const f16* __restrict__ W4T, const float* __restrict__ b4,
    float* __restrict__ out) {
  GEMM_PROLOG
  int m0 = blockIdx.y * 128, n0 = blockIdx.x * 128;
  for (int k0 = 0; k0 < 512; k0 += 32) {
    stage_gll(xln4, 512, m0, k0, As, t);
    stage_gll(W4T, 512, n0, k0, Bs, t);
    __syncthreads();
    mfma_step(As, Bs, lane, wr, wc, acc);
    __syncthreads();
  }
#pragma unroll
  for (int mi = 0; mi < 4; ++mi)
#pragma unroll
    for (int ni = 0; ni < 4; ++ni) {
      int c = n0 + wc * 64 + ni * 16 + (lane & 15);
      float bias = b4[c];
      int r0 = m0 + wr * 64 + mi * 16 + (lane >> 4) * 4;
#pragma unroll
      for (int j = 0; j < 4; ++j)
        out[(long)(r0 + j) * 512 + c] = acc[mi][ni][j] + bias;
    }
}

// ======================= launcher =======================
extern "C" void kernel_launch(void* const* d_in, const int* in_sizes, int n_in,
                              void* d_out, int out_size, void* d_ws, size_t ws_size,
                              hipStream_t stream) {
  const float* x    = (const float*)d_in[0];
  const float* tau  = (const float*)d_in[1];
  const float* g1   = (const float*)d_in[2];
  const float* bl1  = (const float*)d_in[3];
  const float* W1   = (const float*)d_in[4];
  const float* b1   = (const float*)d_in[5];
  const float* g2   = (const float*)d_in[6];
  const float* bl2  = (const float*)d_in[7];
  const float* W2   = (const float*)d_in[8];
  const float* b2   = (const float*)d_in[9];
  const float* g3   = (const float*)d_in[10];
  const float* bl3  = (const float*)d_in[11];
  const float* W3   = (const float*)d_in[12];
  const float* b3   = (const float*)d_in[13];
  const float* g4   = (const float*)d_in[14];
  const float* bl4  = (const float*)d_in[15];
  const float* W4   = (const float*)d_in[16];
  const float* b4   = (const float*)d_in[17];
  float* out = (float*)d_out;

  const long NTOK = (long)B_ * SEQ_;  // 65536

  // ---- workspace layout ----
  char* ws = (char*)d_ws;
  f16* regA   = (f16*)(ws);                         // 64MB: A2 -> xproj -> xln4
  f16* regB   = (f16*)(ws + (64l << 20));           // 64MB: xsum -> rbuf
  float* Zpart = (float*)(ws + (128l << 20));       // 16MB (split-K=2 fp32)
  f16* W2T    = (f16*)(ws + (144l << 20));          // 8MB
  f16* W1T    = (f16*)(ws + (152l << 20));          // 0.5MB
  f16* W3T    = (f16*)(ws + (153l << 20));          // 0.51MB
  f16* W4T    = (f16*)(ws + (154l << 20));          // 0.5MB
  float* xscore = (float*)(ws + (155l << 20));      // 0.25MB
  float* meanA  = (float*)(ws + (156l << 20));      // 0.25MB
  float* rstdA  = meanA + NTOK;                     // 0.25MB
  float* mean2  = rstdA + NTOK;                     // 64KB
  float* rstd2  = mean2 + B_ * 512;                 // 64KB
  float2* part  = (float2*)(rstd2 + B_ * 512);      // 1MB
  f16* ZT     = (f16*)(ws + (157l << 20));          // 4MB

  // ---- d_out (128MB) doubles as scratch, fully overwritten by G4 ----
  f16* xtok   = (f16*)d_out;                               // [0,64) until g2 reads it
  f16* xln1   = (f16*)((char*)d_out + (64l << 20));        // [64,128) before g1; dead after
  f16* xprojT = (f16*)d_out;                               // [0,64) written by g3 (xtok dead)
  f16* Wm     = (f16*)((char*)d_out + (64l << 20));        // [64,80) (xln1 dead by topk)
  f16* WmT    = (f16*)((char*)d_out + (80l << 20));        // [80,96)

  f16* A2    = regA;
  f16* xsum  = regB;
  f16* xproj = regA;   // A2 dead after G2
  f16* rbuf  = regB;   // xsum dead after G3
  f16* xln4  = regA;   // xproj dead after GY

  dim3 tb(32, 8);

  // weight transposes (f16, [n][k])
  transpose_cvt<float><<<dim3(16, 16, 1), tb, 0, stream>>>(W1, W1T, 512, 512, 0, 0);
  transpose_cvt<float><<<dim3(64, 64, 1), tb, 0, stream>>>(W2, W2T, 2048, 2048, 0, 0);
  transpose_cvt<float><<<dim3(17, 16, 1), tb, 0, stream>>>(W3, W3T, 512, 513, 0, 0);
  transpose_cvt<float><<<dim3(16, 16, 1), tb, 0, stream>>>(W4, W4T, 512, 512, 0, 0);

  // 1) fused LN1 -> xln1 (f16), then G1 (pure-gll) -> xtok
  ln_fuse_f32<<<NTOK / 4, 256, 0, stream>>>(x, g1, bl1, xln1);
  g1_kernel<<<dim3(4, 512), 256, 0, stream>>>(xln1, W1T, b1, xtok);

  // 2) LN2 stats + transposed normalize -> A2, then G2 ring -> xsum
  colstats_part<<<B_ * 8, 512, 0, stream>>>(xtok, part);
  colstats_fin<<<64, 256, 0, stream>>>(part, mean2, rstd2);
  trans2_kernel<<<dim3(16, 64, B_), tb, 0, stream>>>(xtok, mean2, rstd2, g2, bl2, A2);
  g2_8p<<<dim3(2, 32, 8), 512, 0, stream>>>(W2T, A2, b2, xtok, xsum);

  // 3) LN3 stats, score column, G3 -> xproj + xprojT (xtok dead)
  rowstats512_f16<<<NTOK / 4, 256, 0, stream>>>(xsum, meanA, rstdA);
  score_kernel<<<NTOK / 4, 256, 0, stream>>>(xsum, meanA, rstdA, g3, bl3, W3T, b3, xscore);
  g3_kernel<<<dim3(4, 512), 256, 0, stream>>>(xsum, meanA, rstdA, g3, bl3, W3T + 512, b3,
                                              xproj, xprojT);

  // 4) top-k -> Wm (f16, d_out[64,80); xln1 dead)
  topk_kernel<<<B_, 512, 0, stream>>>(xscore, tau, Wm);

  // 5) WmT for GY
  transpose_cvt<f16><<<dim3(64, 4, B_), tb, 0, stream>>>(Wm, WmT, 128, 2048,
      (long)KSEL * SEQ_, (long)SEQ_ * KSEL);

  // 6) Z = Wm @ xproj (split-K=2), then reduce+transpose -> ZT
  gz_kernel<<<dim3(4, 2, B_), 256, 0, stream>>>(Wm, xprojT, Zpart);
  ztrans_kernel<<<dim3(16, 4, B_), tb, 0, stream>>>(Zpart, ZT);

  // 7) rbuf = xproj + Wm^T @ Z (overwrites xsum)
  gy_kernel<<<dim3(4, 16, B_), 256, 0, stream>>>(WmT, ZT, xproj, rbuf);

  // 8) fused LN4 -> xln4 (regA; xproj dead), then G4 (pure-gll) -> out
  ln_fuse_f16<<<NTOK / 4, 256, 0, stream>>>(rbuf, g4, bl4, xln4);
  g4_kernel<<<dim3(4, 512), 256, 0, stream>>>(xln4, W4T, b4, out);
}